// Round 7
// baseline (975.248 us; speedup 1.0000x reference)
//
#include <hip/hip_runtime.h>

typedef unsigned long long u64;
typedef unsigned short u16;
typedef unsigned int u32;

// ---------------------------------------------------------------------------
// HierarchicalLFQHVQVAE forward — R15.
// Base = R13/R14 (692/697 us). R14 post-mortem: 2 waves/SIMD achieved (occ
// 22.5%, VGPR 124) but NULL — same-block waves are barrier-locked into the
// same phase, so they contend for one pipe per phase instead of overlapping
// pipes (m114 overlap needs different-phase waves). Also af-from-LDS tripled
// bank conflicts (4.45M->12.7M). The real structure problem: MFMA phase
// (~2500 cyc) and best-2 epilogue VALU phase (~900-1500 cyc) are SERIAL.
// R15: dist2pp — software-pipelined 4-wave z-dist:
//  - two acc sets (named A/B, even/odd unrolled bodies — rule #20);
//  - while MFMA(t) fills acc_cur, the local best-2 of acc_prev is
//    interleaved per-kstep (8 keys/kstep) -> VALU runs in the MFMA shadow;
//  - codebook persistent in LDS (af per-kstep reads; frees 128 VGPR for the
//    2nd acc set); batch single-buffered, stage(t+1) DMA covered by the
//    shfl+wred+merge of t-1 in phase B; 2 barriers/iter.
// q-dist (R11 4-wave dbuf), rerank (R13), GEMMs, prep: unchanged.
// ---------------------------------------------------------------------------

namespace {

constexpr int kBatch = 32768;

__device__ __forceinline__ float gelu_f(float x) {
  return 0.5f * x * (1.0f + erff(x * 0.70710678118654752440f));
}
__device__ __forceinline__ float sigmoid_f(float x) {
  return 1.0f / (1.0f + expf(-x));
}
__device__ __forceinline__ u64 pack_key(float d, unsigned j) {
  unsigned u = __float_as_uint(d);
  u = (u & 0x80000000u) ? ~u : (u | 0x80000000u);
  return ((u64)u << 32) | j;
}
__device__ __forceinline__ u16 bf16_rne(float x) {
  unsigned u = __float_as_uint(x);
  unsigned r = (u + 0x7FFFu + ((u >> 16) & 1u)) >> 16;
  return (u16)r;
}
__device__ __forceinline__ float bf16_to_f(u16 h) {
  return __uint_as_float((unsigned)h << 16);
}
__device__ __forceinline__ u64 min64(u64 a, u64 b) { return a < b ? a : b; }

__device__ __forceinline__ void load_lds16(const void* g, void* l) {
  __builtin_amdgcn_global_load_lds(
      (const __attribute__((address_space(1))) void*)g,
      (__attribute__((address_space(3))) void*)l, 16, 0, 0);
}

template <int N>
__device__ __forceinline__ void wait_vmcnt() {
  if constexpr (N == 0) {
    asm volatile("s_waitcnt vmcnt(0)" ::: "memory");
  } else if constexpr (N == 8) {
    asm volatile("s_waitcnt vmcnt(8)" ::: "memory");
  } else if constexpr (N == 16) {
    asm volatile("s_waitcnt vmcnt(16)" ::: "memory");
  }
}

__device__ __forceinline__ void lds_fence_barrier_pre() {
  // order: all prior LDS ops retired, then barrier
  asm volatile("s_waitcnt lgkmcnt(0)" ::: "memory");
  __builtin_amdgcn_sched_barrier(0);
  __builtin_amdgcn_s_barrier();
  asm volatile("" ::: "memory");  // no LDS op hoists above the barrier
  __builtin_amdgcn_sched_barrier(0);
}

__device__ __forceinline__ void barrier_raw() {
  __builtin_amdgcn_sched_barrier(0);
  __builtin_amdgcn_s_barrier();
  asm volatile("" ::: "memory");  // no LDS op hoists above the barrier
  __builtin_amdgcn_sched_barrier(0);
}

typedef short bf16x8 __attribute__((ext_vector_type(8)));
typedef float f32x4 __attribute__((ext_vector_type(4)));

// ===========================================================================
// Prep (3 kernels) — identical to R6
// ===========================================================================
__global__ void prep_cb_kernel(const float* __restrict__ zcb,
                               u16* __restrict__ zcbh, float* __restrict__ zcbn,
                               const float* __restrict__ qcb,
                               u16* __restrict__ qcbh, float* __restrict__ qcbn) {
  int b = blockIdx.x;
  const float* cb;
  u16* cbh;
  float* cbn;
  int K;
  if (b < 1024) { cb = zcb; cbh = zcbh; cbn = zcbn; K = 256; }
  else { b -= 1024; cb = qcb; cbh = qcbh; cbn = qcbn; K = 128; }
  const int row = b * 4 + (threadIdx.x >> 6);
  const int lane = threadIdx.x & 63;
  double s = 0.0;
  for (int k = lane; k < K; k += 64) {
    const float v = cb[(size_t)row * K + k];
    cbh[(size_t)row * K + k] = bf16_rne(v);
    s += (double)v * (double)v;
  }
#pragma unroll
  for (int o = 32; o > 0; o >>= 1) s += __shfl_down(s, o);
  if (lane == 0) cbn[row] = (float)s;
}

__global__ void prep_w_kernel(
    const float* __restrict__ zW, const float* __restrict__ zci,
    const float* __restrict__ qW, const float* __restrict__ qci,
    const float* __restrict__ eW1, const float* __restrict__ eW2,
    u16* __restrict__ zWns, u16* __restrict__ qWns, u16* __restrict__ eW1s,
    u16* __restrict__ eW2s, const float* __restrict__ dW1,
    const float* __restrict__ dW2, const float* __restrict__ oW,
    u16* __restrict__ dW1b, u16* __restrict__ dW2b, u16* __restrict__ oWb) {
  const int b = blockIdx.x;
  const int tid = threadIdx.x;
  if (b < 384) {
    const float* W;
    const float* ci;
    u16* D;
    int K, row;
    if (b < 256) { W = zW; ci = zci; D = zWns; K = 512; row = b; }
    else { W = qW; ci = qci; D = qWns; K = 256; row = b - 256; }
    float s = 0.f;
    for (int k = tid; k < K; k += 256) s += fabsf(W[(size_t)row * K + k]);
#pragma unroll
    for (int o = 32; o > 0; o >>= 1) s += __shfl_down(s, o);
    __shared__ float p[4];
    if ((tid & 63) == 0) p[tid >> 6] = s;
    __syncthreads();
    const float tot = p[0] + p[1] + p[2] + p[3];
    const float c = ci[row];
    const float sp = (c > 20.f) ? c : log1pf(expf(c));
    const float scale = fminf(1.f, sp / tot);
    for (int k = tid; k < K; k += 256) {
      const float v = W[(size_t)row * K + k] * scale;
      const u16 h = bf16_rne(v);
      const u16 l = bf16_rne(v - bf16_to_f(h));
      D[(size_t)row * 3 * K + k] = h;
      D[(size_t)row * 3 * K + K + k] = h;
      D[(size_t)row * 3 * K + 2 * K + k] = l;
    }
  } else if (b < 512) {  // eW1 split3, 64x512
    const int i = (b - 384) * 256 + tid;
    const int r = i >> 9, k = i & 511;
    const float v = eW1[i];
    const u16 h = bf16_rne(v);
    const u16 l = bf16_rne(v - bf16_to_f(h));
    eW1s[(size_t)r * 1536 + k] = h;
    eW1s[(size_t)r * 1536 + 512 + k] = h;
    eW1s[(size_t)r * 1536 + 1024 + k] = l;
  } else if (b < 640) {  // eW2 split3, 512x64
    const int i = (b - 512) * 256 + tid;
    const int r = i >> 6, k = i & 63;
    const float v = eW2[i];
    const u16 h = bf16_rne(v);
    const u16 l = bf16_rne(v - bf16_to_f(h));
    eW2s[(size_t)r * 192 + k] = h;
    eW2s[(size_t)r * 192 + 64 + k] = h;
    eW2s[(size_t)r * 192 + 128 + k] = l;
  } else if (b < 672) {
    const int i = (b - 640) * 256 + tid;
    dW1b[i] = bf16_rne(dW1[i]);
  } else if (b < 800) {
    const int i = (b - 672) * 256 + tid;
    dW2b[i] = bf16_rne(dW2[i]);
  } else {
    const int i = (b - 800) * 256 + tid;
    oWb[i] = bf16_rne(oW[i]);
  }
}

__global__ void cast_split_x_kernel(const float* __restrict__ x,
                                    u16* __restrict__ xs) {
  const int i = blockIdx.x * 256 + threadIdx.x;
  const int row = i >> 7, c4 = i & 127;
  const float4 v = *(const float4*)(x + (size_t)row * 512 + c4 * 4);
  const float vv[4] = {v.x, v.y, v.z, v.w};
  u16 hv[4], lv[4];
#pragma unroll
  for (int j = 0; j < 4; ++j) {
    hv[j] = bf16_rne(vv[j]);
    lv[j] = bf16_rne(vv[j] - bf16_to_f(hv[j]));
  }
  *(ushort4*)(xs + (size_t)row * 1024 + c4 * 4) =
      make_ushort4(hv[0], hv[1], hv[2], hv[3]);
  *(ushort4*)(xs + (size_t)row * 1024 + 512 + c4 * 4) =
      make_ushort4(lv[0], lv[1], lv[2], lv[3]);
}

// ===========================================================================
// Unified MFMA GEMM (identical to R13).
// ===========================================================================
enum { U_GELU_SPLIT = 0, U_SIG_SPLIT = 1, U_GELU_B16 = 2, U_RECON = 3 };

template <int TM, int TN, int NW, int MODE>
__global__ __launch_bounds__(NW * 64) void gemm_uni(
    const u16* __restrict__ A, const u16* __restrict__ B,
    const float* __restrict__ bias, void* __restrict__ Cv,
    const float* __restrict__ X, float* __restrict__ psum, int Ktot,
    int wrapA, int strideA, int N) {
  __shared__ __align__(16) u16 As[TM * 64];
  __shared__ __align__(16) u16 Bs[TN * 64];
  constexpr int NT = NW * 64;
  constexpr int AIT = (TM * 8) / NT;
  constexpr int BIT = (TN * 8) / NT;
  const int tid = threadIdx.x;
  const int lane = tid & 63, w = tid >> 6;
  const int quad = lane >> 4, l15 = lane & 15;
  const int waveM = (TN == 64) ? w * 64 : (w & 1) * 64;
  const int waveN = (TN == 64) ? 0 : (w >> 1) * 64;
  const int rowBase = blockIdx.y * TM;
  const int colBase = blockIdx.x * TN;

  f32x4 acc[4][4] = {};

  for (int k0 = 0; k0 < Ktot; k0 += 64) {
    const int sk0 = (k0 >= wrapA) ? k0 - wrapA : k0;
    __syncthreads();
#pragma unroll
    for (int i = 0; i < AIT; ++i) {
      const int ch = i * NT + tid;
      const int r = ch >> 3, c = ch & 7, g = c ^ (r & 7);
      load_lds16(A + (size_t)(rowBase + r) * strideA + sk0 + g * 8,
                 (char*)As + ch * 16);
    }
#pragma unroll
    for (int i = 0; i < BIT; ++i) {
      const int ch = i * NT + tid;
      const int r = ch >> 3, c = ch & 7, g = c ^ (r & 7);
      load_lds16(B + (size_t)(colBase + r) * Ktot + k0 + g * 8,
                 (char*)Bs + ch * 16);
    }
    __syncthreads();
#pragma unroll
    for (int ks = 0; ks < 2; ++ks) {
      bf16x8 af[4], bf[4];
      const int ch = ks * 4 + quad;
#pragma unroll
      for (int mi = 0; mi < 4; ++mi) {
        const int rl = waveM + mi * 16 + l15;
        af[mi] = *(const bf16x8*)(As + rl * 64 + (ch ^ (rl & 7)) * 8);
      }
#pragma unroll
      for (int ni = 0; ni < 4; ++ni) {
        const int rl = waveN + ni * 16 + l15;
        bf[ni] = *(const bf16x8*)(Bs + rl * 64 + (ch ^ (rl & 7)) * 8);
      }
#pragma unroll
      for (int mi = 0; mi < 4; ++mi)
#pragma unroll
        for (int ni = 0; ni < 4; ++ni)
          acc[mi][ni] = __builtin_amdgcn_mfma_f32_16x16x32_bf16(
              af[mi], bf[ni], acc[mi][ni], 0, 0, 0);
    }
  }

  if constexpr (MODE == U_GELU_SPLIT || MODE == U_SIG_SPLIT) {
    u16* S = (u16*)Cv;
#pragma unroll
    for (int mi = 0; mi < 4; ++mi)
#pragma unroll
      for (int r = 0; r < 4; ++r) {
        const int row = rowBase + waveM + mi * 16 + quad * 4 + r;
#pragma unroll
        for (int ni = 0; ni < 4; ++ni) {
          const int col = colBase + waveN + ni * 16 + l15;
          const float pre = acc[mi][ni][r] + bias[col];
          const float v = (MODE == U_GELU_SPLIT) ? gelu_f(pre) : sigmoid_f(pre);
          const u16 h = bf16_rne(v);
          const u16 l = bf16_rne(v - bf16_to_f(h));
          S[(size_t)row * 2 * N + col] = h;
          S[(size_t)row * 2 * N + N + col] = l;
        }
      }
  } else if constexpr (MODE == U_GELU_B16) {
    u16* C = (u16*)Cv;
#pragma unroll
    for (int mi = 0; mi < 4; ++mi)
#pragma unroll
      for (int r = 0; r < 4; ++r) {
        const int row = rowBase + waveM + mi * 16 + quad * 4 + r;
#pragma unroll
        for (int ni = 0; ni < 4; ++ni) {
          const int col = colBase + waveN + ni * 16 + l15;
          C[(size_t)row * N + col] =
              bf16_rne(gelu_f(acc[mi][ni][r] + bias[col]));
        }
      }
  } else {  // U_RECON
    float* C = (float*)Cv;
    float local = 0.f;
#pragma unroll
    for (int mi = 0; mi < 4; ++mi)
#pragma unroll
      for (int r = 0; r < 4; ++r) {
        const int row = rowBase + waveM + mi * 16 + quad * 4 + r;
#pragma unroll
        for (int ni = 0; ni < 4; ++ni) {
          const int col = colBase + waveN + ni * 16 + l15;
          const float val = acc[mi][ni][r] + bias[col];
          const float d = val - X[(size_t)row * N + col];
          local += d * d;
          C[(size_t)row * N + col] = val;
        }
      }
#pragma unroll
    for (int o = 32; o > 0; o >>= 1) local += __shfl_down(local, o);
    __shared__ float psh[NW];
    if (lane == 0) psh[w] = local;
    __syncthreads();
    if (tid == 0) {
      float t = 0.f;
#pragma unroll
      for (int i = 0; i < NW; ++i) t += psh[i];
      psum[blockIdx.y * gridDim.x + blockIdx.x] = t;  // unique slot, no atomic
    }
  }
}

// ===========================================================================
// z-level stage-1 distance — R15 software-pipelined 4-wave (dist2pp).
// LDS: bufC codebook persistent 64K, bufB batch single-buffer 64K, wred 2K.
// Per iteration t (2 barriers):
//   phase A: MFMA(t) into acc_cur from bufC/bufB, INTERLEAVED with the
//            local best-2 VALU of acc_prev (8 keys per kstep) — MFMA pipe
//            and VALU pipe concurrently from one wave.
//   lgkm-barrier (bufB reads done)
//   phase B: issue stage(t+1) DMA into bufB; shfl-reduce + wred(t-1) under
//            the DMA; vmcnt(0); lgkm-barrier; merge+store(t-1).
// acc ping-pong via named sets + explicit even/odd bodies (rule #20).
// ===========================================================================
template <int KT, int BTG>
__global__ __launch_bounds__(256) void dist2pp_kernel(
    const u16* __restrict__ CB, const u16* __restrict__ ZB,
    const float* __restrict__ cbn, u32* __restrict__ cand, int strideB,
    int nx) {
  constexpr int CH = KT / 8;               // 32
  constexpr int KSTEPS = KT / 32;          // 8
  constexpr int SLOTS = (128 * CH) / 256;  // 16
  __shared__ __align__(16) u16 bufC[128 * KT];
  __shared__ __align__(16) u16 bufB[128 * KT];
  __shared__ u32 wred[128 * 4];
  const int tid = threadIdx.x;
  const int lane = tid & 63, w = tid >> 6;
  const int quad = lane >> 4, l15 = lane & 15;
  const int waveM = (w & 1) * 64;   // code half
  const int waveN = (w >> 1) * 64;  // batch half
  const int ct = blockIdx.y;
  const int btg = blockIdx.x;
  const int codeBase = ct * 128;

  float cnf[4][4];
#pragma unroll
  for (int mi = 0; mi < 4; ++mi)
#pragma unroll
    for (int r = 0; r < 4; ++r)
      cnf[mi][r] =
          cbn[codeBase + waveM + mi * 16 + quad * 4 + r] * 512.0f + 131072.0f;
  asm volatile("" ::: "memory");

  // ---- stage codebook -> bufC (persistent), tile 0 -> bufB ----
#pragma unroll
  for (int i = 0; i < SLOTS; ++i) {
    const int ch = i * 256 + tid;
    const int r = ch / CH, c = ch % CH, g = c ^ (r & 7);
    load_lds16(CB + (size_t)(codeBase + r) * KT + g * 8, (char*)bufC + ch * 16);
  }
  {
    const int rowBase0 = btg * BTG * 128;
#pragma unroll
    for (int i = 0; i < SLOTS; ++i) {
      const int ch = i * 256 + tid;
      const int r = ch / CH, c = ch % CH, g = c ^ (r & 7);
      load_lds16(ZB + (size_t)(rowBase0 + r) * strideB + g * 8,
                 (char*)bufB + ch * 16);
    }
  }
  wait_vmcnt<0>();
  barrier_raw();

  f32x4 accA[4][4], accB[4][4];

  // ---- t=0 peel: compute accA, no interleave ----
  {
#pragma unroll
    for (int mi = 0; mi < 4; ++mi)
#pragma unroll
      for (int ni = 0; ni < 4; ++ni) accA[mi][ni] = f32x4{0.f, 0.f, 0.f, 0.f};
#pragma unroll
    for (int kk = 0; kk < KSTEPS; ++kk) {
      bf16x8 af[4], bf[4];
#pragma unroll
      for (int mi = 0; mi < 4; ++mi) {
        const int rl = waveM + mi * 16 + l15;
        const int sw = (kk * 4 + quad) ^ (rl & 7);
        af[mi] = *(const bf16x8*)(bufC + rl * KT + sw * 8);
      }
#pragma unroll
      for (int ni = 0; ni < 4; ++ni) {
        const int rn = waveN + ni * 16 + l15;
        const int sw = (kk * 4 + quad) ^ (rn & 7);
        bf[ni] = *(const bf16x8*)(bufB + rn * KT + sw * 8);
      }
#pragma unroll
      for (int mi = 0; mi < 4; ++mi)
#pragma unroll
        for (int ni = 0; ni < 4; ++ni)
          accA[mi][ni] = __builtin_amdgcn_mfma_f32_16x16x32_bf16(
              af[mi], bf[ni], accA[mi][ni], 0, 0, 0);
    }
    lds_fence_barrier_pre();  // bufB(t0) reads done by all waves
    const int rowBase1 = (btg * BTG + 1) * 128;
#pragma unroll
    for (int i = 0; i < SLOTS; ++i) {
      const int ch = i * 256 + tid;
      const int r = ch / CH, c = ch % CH, g = c ^ (r & 7);
      load_lds16(ZB + (size_t)(rowBase1 + r) * strideB + g * 8,
                 (char*)bufB + ch * 16);
    }
    wait_vmcnt<0>();
    barrier_raw();  // bufB(t1) ready
  }

  // ---- pipelined body: compute tile t into cur; finish tile t-1 (prev) ----
  auto body = [&](f32x4(&cur)[4][4], f32x4(&prev)[4][4], int t, bool doStage) {
    u32 pb0[4], pb1[4];
#pragma unroll
    for (int ni = 0; ni < 4; ++ni) { pb0[ni] = ~0u; pb1[ni] = ~0u; }
#pragma unroll
    for (int mi = 0; mi < 4; ++mi)
#pragma unroll
      for (int ni = 0; ni < 4; ++ni) cur[mi][ni] = f32x4{0.f, 0.f, 0.f, 0.f};
    // phase A: MFMA(t) + interleaved local best-2 of prev
#pragma unroll
    for (int kk = 0; kk < KSTEPS; ++kk) {
      bf16x8 af[4], bf[4];
#pragma unroll
      for (int mi = 0; mi < 4; ++mi) {
        const int rl = waveM + mi * 16 + l15;
        const int sw = (kk * 4 + quad) ^ (rl & 7);
        af[mi] = *(const bf16x8*)(bufC + rl * KT + sw * 8);
      }
#pragma unroll
      for (int ni = 0; ni < 4; ++ni) {
        const int rn = waveN + ni * 16 + l15;
        const int sw = (kk * 4 + quad) ^ (rn & 7);
        bf[ni] = *(const bf16x8*)(bufB + rn * KT + sw * 8);
      }
#pragma unroll
      for (int mi = 0; mi < 4; ++mi)
#pragma unroll
        for (int ni = 0; ni < 4; ++ni)
          cur[mi][ni] = __builtin_amdgcn_mfma_f32_16x16x32_bf16(
              af[mi], bf[ni], cur[mi][ni], 0, 0, 0);
      // EPI slice of prev: 8 keys (ni = kk>>1, mi pair = kk&1) — pure VALU
      // on prev's registers, schedulable into the MFMA shadow.
      const int nie = kk >> 1;
#pragma unroll
      for (int m2 = 0; m2 < 2; ++m2) {
        const int mi = (kk & 1) * 2 + m2;
#pragma unroll
        for (int r = 0; r < 4; ++r) {
          const float kf = fmaf(prev[mi][nie][r], -1024.0f, cnf[mi][r]);
          u32 iv = (u32)kf;
          iv = iv > 0xFFFFFu ? 0xFFFFFu : iv;
          const u32 key =
              (iv << 12) | (codeBase + waveM + mi * 16 + quad * 4 + r);
          if (key < pb0[nie]) { pb1[nie] = pb0[nie]; pb0[nie] = key; }
          else if (key < pb1[nie]) { pb1[nie] = key; }
        }
      }
    }
    lds_fence_barrier_pre();  // bufB(t) reads retired by all waves

    // phase B: stage(t+1) DMA under shfl+wred of prev
    if (doStage) {
      const int rowBaseN = (btg * BTG + t + 1) * 128;
#pragma unroll
      for (int i = 0; i < SLOTS; ++i) {
        const int ch = i * 256 + tid;
        const int r = ch / CH, c = ch % CH, g = c ^ (r & 7);
        load_lds16(ZB + (size_t)(rowBaseN + r) * strideB + g * 8,
                   (char*)bufB + ch * 16);
      }
    }
#pragma unroll
    for (int ni = 0; ni < 4; ++ni) {
      u32 b0 = pb0[ni], b1 = pb1[ni];
#pragma unroll
      for (int off = 16; off < 64; off <<= 1) {
        const u32 o0 = __shfl_xor(b0, off);
        const u32 o1 = __shfl_xor(b1, off);
        const u32 n0 = min(b0, o0);
        const u32 n1 = min(max(b0, o0), min(b1, o1));
        b0 = n0; b1 = n1;
      }
      if (quad == 0) {
        const int rloc = waveN + ni * 16 + l15;
        wred[rloc * 4 + (w & 1) * 2 + 0] = b0;
        wred[rloc * 4 + (w & 1) * 2 + 1] = b1;
      }
    }
    wait_vmcnt<0>();          // staged loads landed (covered by shfl above)
    lds_fence_barrier_pre();  // wred visible + bufB(t+1) ready, all waves
    if (tid < 128) {
      const int rowBaseS = (btg * BTG + t - 1) * 128;
      const u32 a0 = wred[tid * 4 + 0], a1 = wred[tid * 4 + 1];
      const u32 c0 = wred[tid * 4 + 2], c1 = wred[tid * 4 + 3];
      const u32 b0 = min(a0, c0);
      const u32 b1 = min(max(a0, c0), min(a1, c1));
      u32* dst = cand + (size_t)(rowBaseS + tid) * (2 * nx) + 2 * ct;
      *(u64*)dst = ((u64)b1 << 32) | b0;
    }
    // merge's ds_reads retire in-order before this wave's next lgkm fence;
    // next wred write is behind the next body's post-compute barrier.
  };

#pragma unroll 1
  for (int p = 0; p < BTG / 2 - 1; ++p) {
    body(accB, accA, 2 * p + 1, true);
    body(accA, accB, 2 * p + 2, true);
  }
  body(accB, accA, BTG - 1, false);

  // ---- final epilogue for tile BTG-1 (accB) ----
  {
    u32 fb0[4], fb1[4];
#pragma unroll
    for (int ni = 0; ni < 4; ++ni) { fb0[ni] = ~0u; fb1[ni] = ~0u; }
#pragma unroll
    for (int ni = 0; ni < 4; ++ni)
#pragma unroll
      for (int mi = 0; mi < 4; ++mi)
#pragma unroll
        for (int r = 0; r < 4; ++r) {
          const float kf = fmaf(accB[mi][ni][r], -1024.0f, cnf[mi][r]);
          u32 iv = (u32)kf;
          iv = iv > 0xFFFFFu ? 0xFFFFFu : iv;
          const u32 key =
              (iv << 12) | (codeBase + waveM + mi * 16 + quad * 4 + r);
          if (key < fb0[ni]) { fb1[ni] = fb0[ni]; fb0[ni] = key; }
          else if (key < fb1[ni]) { fb1[ni] = key; }
        }
    lds_fence_barrier_pre();  // prior merge reads (t=BTG-2) done everywhere
#pragma unroll
    for (int ni = 0; ni < 4; ++ni) {
      u32 b0 = fb0[ni], b1 = fb1[ni];
#pragma unroll
      for (int off = 16; off < 64; off <<= 1) {
        const u32 o0 = __shfl_xor(b0, off);
        const u32 o1 = __shfl_xor(b1, off);
        const u32 n0 = min(b0, o0);
        const u32 n1 = min(max(b0, o0), min(b1, o1));
        b0 = n0; b1 = n1;
      }
      if (quad == 0) {
        const int rloc = waveN + ni * 16 + l15;
        wred[rloc * 4 + (w & 1) * 2 + 0] = b0;
        wred[rloc * 4 + (w & 1) * 2 + 1] = b1;
      }
    }
    lds_fence_barrier_pre();
    if (tid < 128) {
      const int rowBaseS = (btg * BTG + BTG - 1) * 128;
      const u32 a0 = wred[tid * 4 + 0], a1 = wred[tid * 4 + 1];
      const u32 c0 = wred[tid * 4 + 2], c1 = wred[tid * 4 + 3];
      const u32 b0 = min(a0, c0);
      const u32 b1 = min(max(a0, c0), min(a1, c1));
      u32* dst = cand + (size_t)(rowBaseS + tid) * (2 * nx) + 2 * ct;
      *(u64*)dst = ((u64)b1 << 32) | b0;
    }
  }
}

// ===========================================================================
// q-level stage-1 distance — R11 4-wave double-buffered (unchanged).
// ===========================================================================
template <int KT, int BTG>
__global__ __launch_bounds__(256) void dist2p_kernel(
    const u16* __restrict__ CB, const u16* __restrict__ ZB,
    const float* __restrict__ cbn, u32* __restrict__ cand, int strideB,
    int nx) {
  constexpr int CH = KT / 8;            // 16B chunks per row
  constexpr int KSTEPS = KT / 32;       // MFMA k-steps
  constexpr int SLOTS = (128 * CH) / 256;  // loads per thread per tile
  __shared__ __align__(16) u16 bufA[128 * KT];
  __shared__ __align__(16) u16 bufB[128 * KT];
  __shared__ u32 wred[128 * 4];
  const int tid = threadIdx.x;
  const int lane = tid & 63, w = tid >> 6;
  const int quad = lane >> 4, l15 = lane & 15;
  const int waveM = (w & 1) * 64;   // code half
  const int waveN = (w >> 1) * 64;  // batch half
  const int ct = blockIdx.y;
  const int btg = blockIdx.x;
  const int codeBase = ct * 128;

  float cnf[4][4];
#pragma unroll
  for (int mi = 0; mi < 4; ++mi)
#pragma unroll
    for (int r = 0; r < 4; ++r)
      cnf[mi][r] =
          cbn[codeBase + waveM + mi * 16 + quad * 4 + r] * 512.0f + 131072.0f;
  asm volatile("" ::: "memory");

  // ---- stage codebook tile into bufA, batch tile 0 into bufB ----
#pragma unroll
  for (int i = 0; i < SLOTS; ++i) {
    const int ch = i * 256 + tid;
    const int r = ch / CH, c = ch % CH, g = c ^ (r & 7);
    load_lds16(CB + (size_t)(codeBase + r) * KT + g * 8, (char*)bufA + ch * 16);
  }
  {
    const int rowBase0 = btg * BTG * 128;
#pragma unroll
    for (int i = 0; i < SLOTS; ++i) {
      const int ch = i * 256 + tid;
      const int r = ch / CH, c = ch % CH, g = c ^ (r & 7);
      load_lds16(ZB + (size_t)(rowBase0 + r) * strideB + g * 8,
                 (char*)bufB + ch * 16);
    }
  }
  wait_vmcnt<SLOTS>();  // codebook loads retired; t0 loads stay in flight
  barrier_raw();

  // ---- hoist all A fragments from bufA ----
  bf16x8 af[KSTEPS][4];
#pragma unroll
  for (int kk = 0; kk < KSTEPS; ++kk)
#pragma unroll
    for (int mi = 0; mi < 4; ++mi) {
      const int rl = waveM + mi * 16 + l15;
      const int sw = (kk * 4 + quad) ^ (rl & 7);
      af[kk][mi] = *(const bf16x8*)(bufA + rl * KT + sw * 8);
    }
  // bufA free only after ALL waves' af reads retire (t=1 stages into it)
  lds_fence_barrier_pre();

  for (int bt = 0; bt < BTG; ++bt) {
    const int rowBase = (btg * BTG + bt) * 128;
    const u16* curp = (bt & 1) ? bufA : bufB;
    u16* nxtp = (bt & 1) ? bufB : bufA;

    if (bt + 1 < BTG) {
      // issue next tile's staging into the idle buffer
#pragma unroll
      for (int i = 0; i < SLOTS; ++i) {
        const int ch = i * 256 + tid;
        const int r = ch / CH, c = ch % CH, g = c ^ (r & 7);
        load_lds16(ZB + (size_t)(rowBase + 128 + r) * strideB + g * 8,
                   (char*)nxtp + ch * 16);
      }
      wait_vmcnt<SLOTS>();  // cur's loads (+prev store) retired; nxt in flight
    } else {
      wait_vmcnt<0>();
    }
    barrier_raw();  // all waves' cur writes visible

    f32x4 acc[4][4] = {};
#pragma unroll
    for (int kk = 0; kk < KSTEPS; ++kk) {
      bf16x8 bf[4];
#pragma unroll
      for (int ni = 0; ni < 4; ++ni) {
        const int rn = waveN + ni * 16 + l15;
        const int sw = (kk * 4 + quad) ^ (rn & 7);
        bf[ni] = *(const bf16x8*)(curp + rn * KT + sw * 8);
      }
#pragma unroll
      for (int mi = 0; mi < 4; ++mi)
#pragma unroll
        for (int ni = 0; ni < 4; ++ni)
          acc[mi][ni] = __builtin_amdgcn_mfma_f32_16x16x32_bf16(
              af[kk][mi], bf[ni], acc[mi][ni], 0, 0, 0);
    }

#pragma unroll
    for (int ni = 0; ni < 4; ++ni) {
      u32 b0 = ~0u, b1 = ~0u;
#pragma unroll
      for (int mi = 0; mi < 4; ++mi)
#pragma unroll
        for (int r = 0; r < 4; ++r) {
          const float kf = fmaf(acc[mi][ni][r], -1024.0f, cnf[mi][r]);
          u32 iv = (u32)kf;
          iv = iv > 0xFFFFFu ? 0xFFFFFu : iv;
          const u32 key =
              (iv << 12) | (codeBase + waveM + mi * 16 + quad * 4 + r);
          if (key < b0) { b1 = b0; b0 = key; }
          else if (key < b1) { b1 = key; }
        }
#pragma unroll
      for (int off = 16; off < 64; off <<= 1) {
        const u32 o0 = __shfl_xor(b0, off);
        const u32 o1 = __shfl_xor(b1, off);
        const u32 n0 = min(b0, o0);
        const u32 n1 = min(max(b0, o0), min(b1, o1));
        b0 = n0; b1 = n1;
      }
      if (quad == 0) {
        const int rloc = waveN + ni * 16 + l15;
        wred[rloc * 4 + (w & 1) * 2 + 0] = b0;
        wred[rloc * 4 + (w & 1) * 2 + 1] = b1;
      }
    }
    // wred writes + cur bf reads retired, then barrier (cur freed for t+1's
    // STAGE; wred visible for merge)
    lds_fence_barrier_pre();
    if (tid < 128) {
      const u32 a0 = wred[tid * 4 + 0], a1 = wred[tid * 4 + 1];
      const u32 c0 = wred[tid * 4 + 2], c1 = wred[tid * 4 + 3];
      const u32 b0 = min(a0, c0);
      const u32 b1 = min(max(a0, c0), min(a1, c1));
      u32* dst = cand + (size_t)(rowBase + tid) * (2 * nx) + 2 * ct;
      *(u64*)dst = ((u64)b1 << 32) | b0;
    }
    // merge reads of t complete before any wred write of t+1: writers pass
    // the next iteration's barrier first.
  }
}

// ===========================================================================
// Stage-2 rerank — R13 (unchanged).
// ===========================================================================
template <int K, int NC, int LEVEL>
__global__ __launch_bounds__(256, 4) void rerank_kernel(
    const u32* __restrict__ cand, const u16* __restrict__ zes,
    const float* __restrict__ cb, const float* __restrict__ cbn,
    float* __restrict__ outq, u16* __restrict__ wsq,
    float* __restrict__ out_idx, float* __restrict__ psum) {
  constexpr int DV = K / 32;  // float4-chunks per lane dot slice (8 z / 4 q)
  constexpr int MV = K / 64;  // MSE elems per lane (4 z / 2 q)
  const int w = threadIdx.x >> 6, lane = threadIdx.x & 63;
  const int row = blockIdx.x * 4 + w;
  const int g = lane >> 3, sub = lane & 7;

  const u16* zr = zes + (size_t)row * 2 * K;

  // ---- phase 1: batch-issue all row-dependent loads ----
  ushort4 zh[DV], zl[DV];
#pragma unroll
  for (int i = 0; i < DV; ++i) {
    zh[i] = *(const ushort4*)(zr + sub * (K / 8) + 4 * i);
    zl[i] = *(const ushort4*)(zr + K + sub * (K / 8) + 4 * i);
  }
  float zmse[MV];
#pragma unroll
  for (int i = 0; i < MV; ++i) {
    const int c = lane + 64 * i;
    zmse[i] = bf16_to_f(zr[c]) + bf16_to_f(zr[K + c]);
  }
  const u32 mykey = (lane < NC) ? cand[(size_t)row * NC + lane] : ~0u;

  // ---- phase 2: top-8 by rank (LDS broadcast) ----
  __shared__ u32 kb[4][72];
  kb[w][lane] = mykey;
  __syncthreads();
  int rank = 0;
#pragma unroll
  for (int j = 0; j < 64; ++j) {
    const u32 kj = kb[w][j];
    rank += (kj < mykey || (kj == mykey && j < lane)) ? 1 : 0;
  }
  if (rank < 8) kb[w][64 + rank] = mykey;
  __syncthreads();
  const unsigned ci = kb[w][64 + g] & 0xFFFu;

  // ---- phase 3: exact f32 dot for this group's candidate ----
  const float* cr = cb + (size_t)ci * K;
  float dot = 0.f;
#pragma unroll
  for (int i = 0; i < DV; ++i) {
    const float4 cv = *(const float4*)(cr + sub * (K / 8) + 4 * i);
    dot = fmaf(bf16_to_f(zh[i].x) + bf16_to_f(zl[i].x), cv.x, dot);
    dot = fmaf(bf16_to_f(zh[i].y) + bf16_to_f(zl[i].y), cv.y, dot);
    dot = fmaf(bf16_to_f(zh[i].z) + bf16_to_f(zl[i].z), cv.z, dot);
    dot = fmaf(bf16_to_f(zh[i].w) + bf16_to_f(zl[i].w), cv.w, dot);
  }
#pragma unroll
  for (int off = 1; off < 8; off <<= 1) dot += __shfl_xor(dot, off);
  u64 k2 = pack_key(cbn[ci] - 2.0f * dot, ci);
#pragma unroll
  for (int off = 8; off < 64; off <<= 1) k2 = min64(k2, __shfl_xor(k2, off));
  const unsigned best = (unsigned)k2;
  if (lane == 0) out_idx[row] = (float)best;

  // ---- phase 4: gather best row, MSE + writes ----
  const float* br = cb + (size_t)best * K;
  float local = 0.f;
#pragma unroll
  for (int i = 0; i < MV; ++i) {
    const int c = lane + 64 * i;
    const float v = br[c];
    const float d = zmse[i] - v;
    local += d * d;
    outq[(size_t)row * K + c] = v;
    if (LEVEL == 0) {
      const u16 h = bf16_rne(v);
      wsq[(size_t)row * 2 * K + c] = h;
      wsq[(size_t)row * 2 * K + K + c] = bf16_rne(v - bf16_to_f(h));
    } else {
      wsq[(size_t)row * K + c] = bf16_rne(v);
    }
  }
#pragma unroll
  for (int o = 32; o > 0; o >>= 1) local += __shfl_down(local, o);
  __shared__ float p[4];
  if (lane == 0) p[w] = local;
  __syncthreads();
  if (threadIdx.x == 0) psum[blockIdx.x] = p[0] + p[1] + p[2] + p[3];
}

// ===========================================================================
// Finalize: sum the per-block partials (8192 z + 8192 q + 1024 recon).
// ===========================================================================
__global__ void finalize_kernel(const float* __restrict__ psumZ,
                                const float* __restrict__ psumQ,
                                const float* __restrict__ psumR,
                                float* __restrict__ out) {
  const int tid = threadIdx.x;
  float sz = 0.f, sq = 0.f, sr = 0.f;
  for (int i = tid; i < 8192; i += 256) {
    sz += psumZ[i];
    sq += psumQ[i];
  }
  for (int i = tid; i < 1024; i += 256) sr += psumR[i];
#pragma unroll
  for (int o = 32; o > 0; o >>= 1) {
    sz += __shfl_down(sz, o);
    sq += __shfl_down(sq, o);
    sr += __shfl_down(sr, o);
  }
  __shared__ float pz[4], pq[4], pr[4];
  if ((tid & 63) == 0) {
    pz[tid >> 6] = sz;
    pq[tid >> 6] = sq;
    pr[tid >> 6] = sr;
  }
  __syncthreads();
  if (tid == 0) {
    const float cz = (pz[0] + pz[1] + pz[2] + pz[3]) / ((float)kBatch * 256.f);
    const float cq = (pq[0] + pq[1] + pq[2] + pq[3]) / ((float)kBatch * 128.f);
    const float rec = (pr[0] + pr[1] + pr[2] + pr[3]) / ((float)kBatch * 512.f);
    out[0] = rec + 0.5f * cz + 0.5f * cq;
    out[1] = rec;
    out[2] = cz;
    out[3] = cz;
    out[4] = cq;
    out[5] = cq;
  }
}

}  // namespace

extern "C" void kernel_launch(void* const* d_in, const int* in_sizes, int n_in,
                              void* d_out, int out_size, void* d_ws,
                              size_t ws_size, hipStream_t stream) {
  const float* x   = (const float*)d_in[0];
  const float* eW1 = (const float*)d_in[1];
  const float* eb1 = (const float*)d_in[2];
  const float* eW2 = (const float*)d_in[3];
  const float* eb2 = (const float*)d_in[4];
  const float* zW  = (const float*)d_in[5];
  const float* zb  = (const float*)d_in[6];
  const float* zci = (const float*)d_in[7];
  const float* zcb = (const float*)d_in[8];
  const float* qW  = (const float*)d_in[9];
  const float* qb  = (const float*)d_in[10];
  const float* qci = (const float*)d_in[11];
  const float* qcb = (const float*)d_in[12];
  const float* dW1 = (const float*)d_in[13];
  const float* db1 = (const float*)d_in[14];
  const float* dW2 = (const float*)d_in[15];
  const float* db2 = (const float*)d_in[16];
  const float* oW  = (const float*)d_in[17];
  const float* ob  = (const float*)d_in[18];

  float* out = (float*)d_out;
  float* out_xr = out + 6;
  float* out_zq = out_xr + (size_t)32768 * 512;
  float* out_qq = out_zq + (size_t)32768 * 256;
  float* out_zi = out_qq + (size_t)32768 * 128;
  float* out_qi = out_zi + 32768;

  // ---- workspace layout ---------------------------------------------------
  char* wsb = (char*)d_ws;
  u16*  zWns = (u16*) (wsb + 0x0000000);  // 256 x 1536  768K
  u16*  qWns = (u16*) (wsb + 0x00C0000);  // 128 x 768   192K
  u16*  eW1s = (u16*) (wsb + 0x00F0000);  // 64 x 1536   192K
  u16*  eW2s = (u16*) (wsb + 0x0120000);  // 512 x 192   192K
  u16*  dW1b = (u16*) (wsb + 0x0150000);  // 64x128       16K
  u16*  dW2b = (u16*) (wsb + 0x0154000);  // 512x64       64K
  u16*  oWb  = (u16*) (wsb + 0x0164000);  // 512x512     512K
  u16*  zcbh = (u16*) (wsb + 0x01E4000);  // 4096x256      2M
  u16*  qcbh = (u16*) (wsb + 0x03E4000);  // 2048x128    512K
  float* zcbn = (float*)(wsb + 0x0464000); // 16K
  float* qcbn = (float*)(wsb + 0x0468000); // 8K
  float* psumR = (float*)(wsb + 0x046B000); // 1024 f32 = 4K
  float* psumZ = (float*)(wsb + 0x0470000); // 8192 f32 = 32K
  float* psumQ = (float*)(wsb + 0x0478000); // 8192 f32 = 32K
  // time-windowed regions:
  u16*  h1s  = (u16*) (wsb + 0x0480000);  // 8M  [enc1 -> enc2]
  u16*  h1b  = (u16*) (wsb + 0x0480000);  //   4M [dec1 -> dec2]
  u16*  zes  = (u16*) (wsb + 0x0C80000);  // 32M [zproj -> zdist,zrerank]
  u16*  qes  = (u16*) (wsb + 0x0C80000);  //   16M [qproj -> qdist,qrerank]
  u16*  hb   = (u16*) (wsb + 0x0C80000);  //   32M [dec2 -> recon]
  u16*  xs   = (u16*) (wsb + 0x2C80000);  // 64M [cast -> enc1]
  u16*  hs   = (u16*) (wsb + 0x2C80000);  //   64M [enc2 -> zproj]
  u32*  candz = (u32*)(wsb + 0x2C80000);  //   8M [zdist -> zrerank]
  u16*  zqs  = (u16*) (wsb + 0x3480000);  //   32M [zrerank -> qproj]
  u32*  candq = (u32*)(wsb + 0x2C80000);  //   4M [qdist -> qrerank]
  u16*  qqb  = (u16*) (wsb + 0x5480000);  //   8M [qrerank -> dec1]

  // ---- prep (3 launches; no memset needed — partials are plain stores) ----
  prep_cb_kernel<<<1536, 256, 0, stream>>>(zcb, zcbh, zcbn, qcb, qcbh, qcbn);
  prep_w_kernel<<<1824, 256, 0, stream>>>(zW, zci, qW, qci, eW1, eW2, zWns,
                                          qWns, eW1s, eW2s, dW1, dW2, oW,
                                          dW1b, dW2b, oWb);
  cast_split_x_kernel<<<16384, 256, 0, stream>>>(x, xs);

  // ---- encoder ----
  gemm_uni<128, 64, 2, U_GELU_SPLIT><<<dim3(1, 256), 128, 0, stream>>>(
      xs, eW1s, eb1, h1s, nullptr, nullptr, 1536, 1024, 1024, 64);
  gemm_uni<128, 128, 4, U_GELU_SPLIT><<<dim3(4, 256), 256, 0, stream>>>(
      h1s, eW2s, eb2, hs, nullptr, nullptr, 192, 128, 128, 512);
  gemm_uni<128, 128, 4, U_SIG_SPLIT><<<dim3(2, 256), 256, 0, stream>>>(
      hs, zWns, zb, zes, nullptr, nullptr, 1536, 1024, 1024, 256);

  // ---- z quantize: pipelined 4-wave dist2pp, grid (btg=8, ct=32), 1/CU
  dist2pp_kernel<256, 32><<<dim3(8, 32), 256, 0, stream>>>(
      zcbh, zes, zcbn, candz, 512, 32);
  rerank_kernel<256, 64, 0><<<8192, 256, 0, stream>>>(
      candz, zes, zcb, zcbn, out_zq, zqs, out_zi, psumZ);

  // ---- q level ----
  gemm_uni<128, 128, 4, U_SIG_SPLIT><<<dim3(1, 256), 256, 0, stream>>>(
      zqs, qWns, qb, qes, nullptr, nullptr, 768, 512, 512, 128);
  dist2p_kernel<128, 8><<<dim3(32, 16), 256, 0, stream>>>(
      qcbh, qes, qcbn, candq, 256, 16);
  rerank_kernel<128, 32, 1><<<8192, 256, 0, stream>>>(
      candq, qes, qcb, qcbn, out_qq, qqb, out_qi, psumQ);

  // ---- decoder ----
  gemm_uni<128, 64, 2, U_GELU_B16><<<dim3(1, 256), 128, 0, stream>>>(
      qqb, dW1b, db1, h1b, nullptr, nullptr, 128, 1 << 30, 128, 64);
  gemm_uni<128, 128, 4, U_GELU_B16><<<dim3(4, 256), 256, 0, stream>>>(
      h1b, dW2b, db2, hb, nullptr, nullptr, 64, 1 << 30, 64, 512);
  gemm_uni<128, 128, 4, U_RECON><<<dim3(4, 256), 256, 0, stream>>>(
      hb, oWb, ob, out_xr, x, psumR, 512, 1 << 30, 512, 512);

  finalize_kernel<<<1, 256, 0, stream>>>(psumZ, psumQ, psumR, out);

  (void)in_sizes; (void)n_in; (void)out_size; (void)ws_size;
}

// Round 8
// 689.527 us; speedup vs baseline: 1.4144x; 1.4144x over previous
//
#include <hip/hip_runtime.h>

typedef unsigned long long u64;
typedef unsigned short u16;
typedef unsigned int u32;

// ---------------------------------------------------------------------------
// HierarchicalLFQHVQVAE forward — R16.
// Base = R13 (692 us). R15 (in-wave pipelining) REGRESSED (VGPR 192, 172us)
// — reverted. Ledger for z-dist: in-block wave pairs are barrier-locked
// (R14 null); in-wave interleave register-starves (R15); the only mechanism
// that raised utilization was a 2nd INDEPENDENT block/CU (R9), blocked only
// by the 2-block packing budget (VGPR<=128, LDS<=80K/block).
// R16: dist2z — shrink the block until two fit, KEEPING the af-hoist:
//  - 64 codes x 64 batch rows per block: bufC 32K + bufB 32K + wred 0.5K
//    = 66K <= 80K; af[8][2] hoist = 64 VGPR -> total ~110 <= 128.
//  - grid (8,64) = 512 blocks = exactly 2/CU; lin%8==btg -> both resident
//    blocks share one batch window (stage L2-hits) on one XCD.
//  - selection: top-1 per 64-code tile (64 cands, cand[row*64+ct], NC=64)
//    -> rerank byte-compatible; global-best code still always a candidate
//    with minimal key -> exact top-8 rerank unchanged in guarantee.
//  - per iter: MFMA -> epi -> fence -> issue stage(t+1) -> merge under DMA
//    -> vmcnt(0)+fence. Cross-block overlap hides the serial phases.
// q-dist (R11 dbuf), rerank (R13), GEMMs, prep: unchanged.
// ---------------------------------------------------------------------------

namespace {

constexpr int kBatch = 32768;

__device__ __forceinline__ float gelu_f(float x) {
  return 0.5f * x * (1.0f + erff(x * 0.70710678118654752440f));
}
__device__ __forceinline__ float sigmoid_f(float x) {
  return 1.0f / (1.0f + expf(-x));
}
__device__ __forceinline__ u64 pack_key(float d, unsigned j) {
  unsigned u = __float_as_uint(d);
  u = (u & 0x80000000u) ? ~u : (u | 0x80000000u);
  return ((u64)u << 32) | j;
}
__device__ __forceinline__ u16 bf16_rne(float x) {
  unsigned u = __float_as_uint(x);
  unsigned r = (u + 0x7FFFu + ((u >> 16) & 1u)) >> 16;
  return (u16)r;
}
__device__ __forceinline__ float bf16_to_f(u16 h) {
  return __uint_as_float((unsigned)h << 16);
}
__device__ __forceinline__ u64 min64(u64 a, u64 b) { return a < b ? a : b; }

__device__ __forceinline__ void load_lds16(const void* g, void* l) {
  __builtin_amdgcn_global_load_lds(
      (const __attribute__((address_space(1))) void*)g,
      (__attribute__((address_space(3))) void*)l, 16, 0, 0);
}

template <int N>
__device__ __forceinline__ void wait_vmcnt() {
  if constexpr (N == 0) {
    asm volatile("s_waitcnt vmcnt(0)" ::: "memory");
  } else if constexpr (N == 8) {
    asm volatile("s_waitcnt vmcnt(8)" ::: "memory");
  } else if constexpr (N == 16) {
    asm volatile("s_waitcnt vmcnt(16)" ::: "memory");
  }
}

__device__ __forceinline__ void lds_fence_barrier_pre() {
  // order: all prior LDS ops retired, then barrier
  asm volatile("s_waitcnt lgkmcnt(0)" ::: "memory");
  __builtin_amdgcn_sched_barrier(0);
  __builtin_amdgcn_s_barrier();
  asm volatile("" ::: "memory");  // no LDS op hoists above the barrier
  __builtin_amdgcn_sched_barrier(0);
}

__device__ __forceinline__ void barrier_raw() {
  __builtin_amdgcn_sched_barrier(0);
  __builtin_amdgcn_s_barrier();
  asm volatile("" ::: "memory");  // no LDS op hoists above the barrier
  __builtin_amdgcn_sched_barrier(0);
}

typedef short bf16x8 __attribute__((ext_vector_type(8)));
typedef float f32x4 __attribute__((ext_vector_type(4)));

// ===========================================================================
// Prep (3 kernels) — identical to R6
// ===========================================================================
__global__ void prep_cb_kernel(const float* __restrict__ zcb,
                               u16* __restrict__ zcbh, float* __restrict__ zcbn,
                               const float* __restrict__ qcb,
                               u16* __restrict__ qcbh, float* __restrict__ qcbn) {
  int b = blockIdx.x;
  const float* cb;
  u16* cbh;
  float* cbn;
  int K;
  if (b < 1024) { cb = zcb; cbh = zcbh; cbn = zcbn; K = 256; }
  else { b -= 1024; cb = qcb; cbh = qcbh; cbn = qcbn; K = 128; }
  const int row = b * 4 + (threadIdx.x >> 6);
  const int lane = threadIdx.x & 63;
  double s = 0.0;
  for (int k = lane; k < K; k += 64) {
    const float v = cb[(size_t)row * K + k];
    cbh[(size_t)row * K + k] = bf16_rne(v);
    s += (double)v * (double)v;
  }
#pragma unroll
  for (int o = 32; o > 0; o >>= 1) s += __shfl_down(s, o);
  if (lane == 0) cbn[row] = (float)s;
}

__global__ void prep_w_kernel(
    const float* __restrict__ zW, const float* __restrict__ zci,
    const float* __restrict__ qW, const float* __restrict__ qci,
    const float* __restrict__ eW1, const float* __restrict__ eW2,
    u16* __restrict__ zWns, u16* __restrict__ qWns, u16* __restrict__ eW1s,
    u16* __restrict__ eW2s, const float* __restrict__ dW1,
    const float* __restrict__ dW2, const float* __restrict__ oW,
    u16* __restrict__ dW1b, u16* __restrict__ dW2b, u16* __restrict__ oWb) {
  const int b = blockIdx.x;
  const int tid = threadIdx.x;
  if (b < 384) {
    const float* W;
    const float* ci;
    u16* D;
    int K, row;
    if (b < 256) { W = zW; ci = zci; D = zWns; K = 512; row = b; }
    else { W = qW; ci = qci; D = qWns; K = 256; row = b - 256; }
    float s = 0.f;
    for (int k = tid; k < K; k += 256) s += fabsf(W[(size_t)row * K + k]);
#pragma unroll
    for (int o = 32; o > 0; o >>= 1) s += __shfl_down(s, o);
    __shared__ float p[4];
    if ((tid & 63) == 0) p[tid >> 6] = s;
    __syncthreads();
    const float tot = p[0] + p[1] + p[2] + p[3];
    const float c = ci[row];
    const float sp = (c > 20.f) ? c : log1pf(expf(c));
    const float scale = fminf(1.f, sp / tot);
    for (int k = tid; k < K; k += 256) {
      const float v = W[(size_t)row * K + k] * scale;
      const u16 h = bf16_rne(v);
      const u16 l = bf16_rne(v - bf16_to_f(h));
      D[(size_t)row * 3 * K + k] = h;
      D[(size_t)row * 3 * K + K + k] = h;
      D[(size_t)row * 3 * K + 2 * K + k] = l;
    }
  } else if (b < 512) {  // eW1 split3, 64x512
    const int i = (b - 384) * 256 + tid;
    const int r = i >> 9, k = i & 511;
    const float v = eW1[i];
    const u16 h = bf16_rne(v);
    const u16 l = bf16_rne(v - bf16_to_f(h));
    eW1s[(size_t)r * 1536 + k] = h;
    eW1s[(size_t)r * 1536 + 512 + k] = h;
    eW1s[(size_t)r * 1536 + 1024 + k] = l;
  } else if (b < 640) {  // eW2 split3, 512x64
    const int i = (b - 512) * 256 + tid;
    const int r = i >> 6, k = i & 63;
    const float v = eW2[i];
    const u16 h = bf16_rne(v);
    const u16 l = bf16_rne(v - bf16_to_f(h));
    eW2s[(size_t)r * 192 + k] = h;
    eW2s[(size_t)r * 192 + 64 + k] = h;
    eW2s[(size_t)r * 192 + 128 + k] = l;
  } else if (b < 672) {
    const int i = (b - 640) * 256 + tid;
    dW1b[i] = bf16_rne(dW1[i]);
  } else if (b < 800) {
    const int i = (b - 672) * 256 + tid;
    dW2b[i] = bf16_rne(dW2[i]);
  } else {
    const int i = (b - 800) * 256 + tid;
    oWb[i] = bf16_rne(oW[i]);
  }
}

__global__ void cast_split_x_kernel(const float* __restrict__ x,
                                    u16* __restrict__ xs) {
  const int i = blockIdx.x * 256 + threadIdx.x;
  const int row = i >> 7, c4 = i & 127;
  const float4 v = *(const float4*)(x + (size_t)row * 512 + c4 * 4);
  const float vv[4] = {v.x, v.y, v.z, v.w};
  u16 hv[4], lv[4];
#pragma unroll
  for (int j = 0; j < 4; ++j) {
    hv[j] = bf16_rne(vv[j]);
    lv[j] = bf16_rne(vv[j] - bf16_to_f(hv[j]));
  }
  *(ushort4*)(xs + (size_t)row * 1024 + c4 * 4) =
      make_ushort4(hv[0], hv[1], hv[2], hv[3]);
  *(ushort4*)(xs + (size_t)row * 1024 + 512 + c4 * 4) =
      make_ushort4(lv[0], lv[1], lv[2], lv[3]);
}

// ===========================================================================
// Unified MFMA GEMM (identical to R13).
// ===========================================================================
enum { U_GELU_SPLIT = 0, U_SIG_SPLIT = 1, U_GELU_B16 = 2, U_RECON = 3 };

template <int TM, int TN, int NW, int MODE>
__global__ __launch_bounds__(NW * 64) void gemm_uni(
    const u16* __restrict__ A, const u16* __restrict__ B,
    const float* __restrict__ bias, void* __restrict__ Cv,
    const float* __restrict__ X, float* __restrict__ psum, int Ktot,
    int wrapA, int strideA, int N) {
  __shared__ __align__(16) u16 As[TM * 64];
  __shared__ __align__(16) u16 Bs[TN * 64];
  constexpr int NT = NW * 64;
  constexpr int AIT = (TM * 8) / NT;
  constexpr int BIT = (TN * 8) / NT;
  const int tid = threadIdx.x;
  const int lane = tid & 63, w = tid >> 6;
  const int quad = lane >> 4, l15 = lane & 15;
  const int waveM = (TN == 64) ? w * 64 : (w & 1) * 64;
  const int waveN = (TN == 64) ? 0 : (w >> 1) * 64;
  const int rowBase = blockIdx.y * TM;
  const int colBase = blockIdx.x * TN;

  f32x4 acc[4][4] = {};

  for (int k0 = 0; k0 < Ktot; k0 += 64) {
    const int sk0 = (k0 >= wrapA) ? k0 - wrapA : k0;
    __syncthreads();
#pragma unroll
    for (int i = 0; i < AIT; ++i) {
      const int ch = i * NT + tid;
      const int r = ch >> 3, c = ch & 7, g = c ^ (r & 7);
      load_lds16(A + (size_t)(rowBase + r) * strideA + sk0 + g * 8,
                 (char*)As + ch * 16);
    }
#pragma unroll
    for (int i = 0; i < BIT; ++i) {
      const int ch = i * NT + tid;
      const int r = ch >> 3, c = ch & 7, g = c ^ (r & 7);
      load_lds16(B + (size_t)(colBase + r) * Ktot + k0 + g * 8,
                 (char*)Bs + ch * 16);
    }
    __syncthreads();
#pragma unroll
    for (int ks = 0; ks < 2; ++ks) {
      bf16x8 af[4], bf[4];
      const int ch = ks * 4 + quad;
#pragma unroll
      for (int mi = 0; mi < 4; ++mi) {
        const int rl = waveM + mi * 16 + l15;
        af[mi] = *(const bf16x8*)(As + rl * 64 + (ch ^ (rl & 7)) * 8);
      }
#pragma unroll
      for (int ni = 0; ni < 4; ++ni) {
        const int rl = waveN + ni * 16 + l15;
        bf[ni] = *(const bf16x8*)(Bs + rl * 64 + (ch ^ (rl & 7)) * 8);
      }
#pragma unroll
      for (int mi = 0; mi < 4; ++mi)
#pragma unroll
        for (int ni = 0; ni < 4; ++ni)
          acc[mi][ni] = __builtin_amdgcn_mfma_f32_16x16x32_bf16(
              af[mi], bf[ni], acc[mi][ni], 0, 0, 0);
    }
  }

  if constexpr (MODE == U_GELU_SPLIT || MODE == U_SIG_SPLIT) {
    u16* S = (u16*)Cv;
#pragma unroll
    for (int mi = 0; mi < 4; ++mi)
#pragma unroll
      for (int r = 0; r < 4; ++r) {
        const int row = rowBase + waveM + mi * 16 + quad * 4 + r;
#pragma unroll
        for (int ni = 0; ni < 4; ++ni) {
          const int col = colBase + waveN + ni * 16 + l15;
          const float pre = acc[mi][ni][r] + bias[col];
          const float v = (MODE == U_GELU_SPLIT) ? gelu_f(pre) : sigmoid_f(pre);
          const u16 h = bf16_rne(v);
          const u16 l = bf16_rne(v - bf16_to_f(h));
          S[(size_t)row * 2 * N + col] = h;
          S[(size_t)row * 2 * N + N + col] = l;
        }
      }
  } else if constexpr (MODE == U_GELU_B16) {
    u16* C = (u16*)Cv;
#pragma unroll
    for (int mi = 0; mi < 4; ++mi)
#pragma unroll
      for (int r = 0; r < 4; ++r) {
        const int row = rowBase + waveM + mi * 16 + quad * 4 + r;
#pragma unroll
        for (int ni = 0; ni < 4; ++ni) {
          const int col = colBase + waveN + ni * 16 + l15;
          C[(size_t)row * N + col] =
              bf16_rne(gelu_f(acc[mi][ni][r] + bias[col]));
        }
      }
  } else {  // U_RECON
    float* C = (float*)Cv;
    float local = 0.f;
#pragma unroll
    for (int mi = 0; mi < 4; ++mi)
#pragma unroll
      for (int r = 0; r < 4; ++r) {
        const int row = rowBase + waveM + mi * 16 + quad * 4 + r;
#pragma unroll
        for (int ni = 0; ni < 4; ++ni) {
          const int col = colBase + waveN + ni * 16 + l15;
          const float val = acc[mi][ni][r] + bias[col];
          const float d = val - X[(size_t)row * N + col];
          local += d * d;
          C[(size_t)row * N + col] = val;
        }
      }
#pragma unroll
    for (int o = 32; o > 0; o >>= 1) local += __shfl_down(local, o);
    __shared__ float psh[NW];
    if (lane == 0) psh[w] = local;
    __syncthreads();
    if (tid == 0) {
      float t = 0.f;
#pragma unroll
      for (int i = 0; i < NW; ++i) t += psh[i];
      psum[blockIdx.y * gridDim.x + blockIdx.x] = t;  // unique slot, no atomic
    }
  }
}

// ===========================================================================
// z-level stage-1 distance — R16 dist2z: 64 codes x 64 rows, 2 blocks/CU.
// bufC (codebook, 32K) persistent + af[8][2] hoist (64 VGPR); bufB (batch,
// 32K) single-buffered. 4 waves: 2 code-halves (32) x 2 batch-halves (32),
// acc[2][2]. Top-1 per tile -> cand[row*64 + ct] (NC=64, rerank-compatible).
// Per iter: MFMA -> epi -> fence -> issue stage(t+1) -> merge under DMA ->
// vmcnt(0) -> fence. The co-resident 2nd block covers exposed phases.
// ===========================================================================
template <int KT, int CT, int BR, int BTG>
__global__ __launch_bounds__(256) void dist2z_kernel(
    const u16* __restrict__ CB, const u16* __restrict__ ZB,
    const float* __restrict__ cbn, u32* __restrict__ cand, int strideB,
    int ncand) {
  constexpr int CH = KT / 8;               // 32 16B-chunks per row
  constexpr int KSTEPS = KT / 32;          // 8
  constexpr int CSLOTS = (CT * CH) / 256;  // 8
  constexpr int BSLOTS = (BR * CH) / 256;  // 8
  __shared__ __align__(16) u16 bufC[CT * KT];  // 32K codebook, persistent
  __shared__ __align__(16) u16 bufB[BR * KT];  // 32K batch tile
  __shared__ u32 wred[BR * 2];
  const int tid = threadIdx.x;
  const int lane = tid & 63, w = tid >> 6;
  const int quad = lane >> 4, l15 = lane & 15;
  const int waveM = (w & 1) * 32;   // code half (32 codes)
  const int waveN = (w >> 1) * 32;  // batch half (32 rows)
  const int ct = blockIdx.y;
  const int btg = blockIdx.x;
  const int codeBase = ct * CT;

  float cnf[2][4];
#pragma unroll
  for (int mi = 0; mi < 2; ++mi)
#pragma unroll
    for (int r = 0; r < 4; ++r)
      cnf[mi][r] =
          cbn[codeBase + waveM + mi * 16 + quad * 4 + r] * 512.0f + 131072.0f;
  asm volatile("" ::: "memory");

  // ---- stage codebook -> bufC, batch tile 0 -> bufB ----
#pragma unroll
  for (int i = 0; i < CSLOTS; ++i) {
    const int ch = i * 256 + tid;
    const int r = ch / CH, c = ch % CH, g = c ^ (r & 7);
    load_lds16(CB + (size_t)(codeBase + r) * KT + g * 8, (char*)bufC + ch * 16);
  }
  {
    const int rowBase0 = btg * BTG * BR;
#pragma unroll
    for (int i = 0; i < BSLOTS; ++i) {
      const int ch = i * 256 + tid;
      const int r = ch / CH, c = ch % CH, g = c ^ (r & 7);
      load_lds16(ZB + (size_t)(rowBase0 + r) * strideB + g * 8,
                 (char*)bufB + ch * 16);
    }
  }
  wait_vmcnt<0>();
  barrier_raw();

  // ---- hoist A fragments (64 VGPR); bufC never written again ----
  bf16x8 af[KSTEPS][2];
#pragma unroll
  for (int kk = 0; kk < KSTEPS; ++kk)
#pragma unroll
    for (int mi = 0; mi < 2; ++mi) {
      const int rl = waveM + mi * 16 + l15;
      const int sw = (kk * 4 + quad) ^ (rl & 7);
      af[kk][mi] = *(const bf16x8*)(bufC + rl * KT + sw * 8);
    }

#pragma unroll 1
  for (int bt = 0; bt < BTG; ++bt) {
    const int rowBase = (btg * BTG + bt) * BR;

    // ---- MFMA over bufB(bt) ----
    f32x4 acc[2][2] = {};
#pragma unroll
    for (int kk = 0; kk < KSTEPS; ++kk) {
      bf16x8 bf[2];
#pragma unroll
      for (int ni = 0; ni < 2; ++ni) {
        const int rn = waveN + ni * 16 + l15;
        const int sw = (kk * 4 + quad) ^ (rn & 7);
        bf[ni] = *(const bf16x8*)(bufB + rn * KT + sw * 8);
      }
#pragma unroll
      for (int mi = 0; mi < 2; ++mi)
#pragma unroll
        for (int ni = 0; ni < 2; ++ni)
          acc[mi][ni] = __builtin_amdgcn_mfma_f32_16x16x32_bf16(
              af[kk][mi], bf[ni], acc[mi][ni], 0, 0, 0);
    }

    // ---- epilogue: top-1 per batch row over this wave's 32 codes ----
#pragma unroll
    for (int ni = 0; ni < 2; ++ni) {
      u32 b0 = ~0u;
#pragma unroll
      for (int mi = 0; mi < 2; ++mi)
#pragma unroll
        for (int r = 0; r < 4; ++r) {
          const float kf = fmaf(acc[mi][ni][r], -1024.0f, cnf[mi][r]);
          u32 iv = (u32)kf;
          iv = iv > 0xFFFFFu ? 0xFFFFFu : iv;
          const u32 key =
              (iv << 12) | (codeBase + waveM + mi * 16 + quad * 4 + r);
          b0 = min(b0, key);
        }
      b0 = min(b0, (u32)__shfl_xor(b0, 16));
      b0 = min(b0, (u32)__shfl_xor(b0, 32));
      if (quad == 0) {
        const int rloc = waveN + ni * 16 + l15;
        wred[rloc * 2 + (w & 1)] = b0;
      }
    }
    // bufB reads + wred writes retired, then barrier
    lds_fence_barrier_pre();

    // ---- issue next tile's staging (DMA runs under the merge) ----
    if (bt + 1 < BTG) {
      const int rowBaseN = rowBase + BR;
#pragma unroll
      for (int i = 0; i < BSLOTS; ++i) {
        const int ch = i * 256 + tid;
        const int r = ch / CH, c = ch % CH, g = c ^ (r & 7);
        load_lds16(ZB + (size_t)(rowBaseN + r) * strideB + g * 8,
                   (char*)bufB + ch * 16);
      }
    }
    // ---- merge + store (reads wred(bt), safe vs stage: different region) --
    if (tid < BR) {
      const u32 m0 = min(wred[tid * 2 + 0], wred[tid * 2 + 1]);
      cand[(size_t)(rowBase + tid) * ncand + ct] = m0;
    }
    wait_vmcnt<0>();          // bufB(bt+1) landed (+ cand store retired)
    lds_fence_barrier_pre();  // visible to all; merge reads drained
  }
}

// ===========================================================================
// q-level stage-1 distance — R11 4-wave double-buffered (unchanged).
// ===========================================================================
template <int KT, int BTG>
__global__ __launch_bounds__(256) void dist2p_kernel(
    const u16* __restrict__ CB, const u16* __restrict__ ZB,
    const float* __restrict__ cbn, u32* __restrict__ cand, int strideB,
    int nx) {
  constexpr int CH = KT / 8;            // 16B chunks per row
  constexpr int KSTEPS = KT / 32;       // MFMA k-steps
  constexpr int SLOTS = (128 * CH) / 256;  // loads per thread per tile
  __shared__ __align__(16) u16 bufA[128 * KT];
  __shared__ __align__(16) u16 bufB[128 * KT];
  __shared__ u32 wred[128 * 4];
  const int tid = threadIdx.x;
  const int lane = tid & 63, w = tid >> 6;
  const int quad = lane >> 4, l15 = lane & 15;
  const int waveM = (w & 1) * 64;   // code half
  const int waveN = (w >> 1) * 64;  // batch half
  const int ct = blockIdx.y;
  const int btg = blockIdx.x;
  const int codeBase = ct * 128;

  float cnf[4][4];
#pragma unroll
  for (int mi = 0; mi < 4; ++mi)
#pragma unroll
    for (int r = 0; r < 4; ++r)
      cnf[mi][r] =
          cbn[codeBase + waveM + mi * 16 + quad * 4 + r] * 512.0f + 131072.0f;
  asm volatile("" ::: "memory");

  // ---- stage codebook tile into bufA, batch tile 0 into bufB ----
#pragma unroll
  for (int i = 0; i < SLOTS; ++i) {
    const int ch = i * 256 + tid;
    const int r = ch / CH, c = ch % CH, g = c ^ (r & 7);
    load_lds16(CB + (size_t)(codeBase + r) * KT + g * 8, (char*)bufA + ch * 16);
  }
  {
    const int rowBase0 = btg * BTG * 128;
#pragma unroll
    for (int i = 0; i < SLOTS; ++i) {
      const int ch = i * 256 + tid;
      const int r = ch / CH, c = ch % CH, g = c ^ (r & 7);
      load_lds16(ZB + (size_t)(rowBase0 + r) * strideB + g * 8,
                 (char*)bufB + ch * 16);
    }
  }
  wait_vmcnt<SLOTS>();  // codebook loads retired; t0 loads stay in flight
  barrier_raw();

  // ---- hoist all A fragments from bufA ----
  bf16x8 af[KSTEPS][4];
#pragma unroll
  for (int kk = 0; kk < KSTEPS; ++kk)
#pragma unroll
    for (int mi = 0; mi < 4; ++mi) {
      const int rl = waveM + mi * 16 + l15;
      const int sw = (kk * 4 + quad) ^ (rl & 7);
      af[kk][mi] = *(const bf16x8*)(bufA + rl * KT + sw * 8);
    }
  // bufA free only after ALL waves' af reads retire (t=1 stages into it)
  lds_fence_barrier_pre();

  for (int bt = 0; bt < BTG; ++bt) {
    const int rowBase = (btg * BTG + bt) * 128;
    const u16* curp = (bt & 1) ? bufA : bufB;
    u16* nxtp = (bt & 1) ? bufB : bufA;

    if (bt + 1 < BTG) {
      // issue next tile's staging into the idle buffer
#pragma unroll
      for (int i = 0; i < SLOTS; ++i) {
        const int ch = i * 256 + tid;
        const int r = ch / CH, c = ch % CH, g = c ^ (r & 7);
        load_lds16(ZB + (size_t)(rowBase + 128 + r) * strideB + g * 8,
                   (char*)nxtp + ch * 16);
      }
      wait_vmcnt<SLOTS>();  // cur's loads (+prev store) retired; nxt in flight
    } else {
      wait_vmcnt<0>();
    }
    barrier_raw();  // all waves' cur writes visible

    f32x4 acc[4][4] = {};
#pragma unroll
    for (int kk = 0; kk < KSTEPS; ++kk) {
      bf16x8 bf[4];
#pragma unroll
      for (int ni = 0; ni < 4; ++ni) {
        const int rn = waveN + ni * 16 + l15;
        const int sw = (kk * 4 + quad) ^ (rn & 7);
        bf[ni] = *(const bf16x8*)(curp + rn * KT + sw * 8);
      }
#pragma unroll
      for (int mi = 0; mi < 4; ++mi)
#pragma unroll
        for (int ni = 0; ni < 4; ++ni)
          acc[mi][ni] = __builtin_amdgcn_mfma_f32_16x16x32_bf16(
              af[kk][mi], bf[ni], acc[mi][ni], 0, 0, 0);
    }

#pragma unroll
    for (int ni = 0; ni < 4; ++ni) {
      u32 b0 = ~0u, b1 = ~0u;
#pragma unroll
      for (int mi = 0; mi < 4; ++mi)
#pragma unroll
        for (int r = 0; r < 4; ++r) {
          const float kf = fmaf(acc[mi][ni][r], -1024.0f, cnf[mi][r]);
          u32 iv = (u32)kf;
          iv = iv > 0xFFFFFu ? 0xFFFFFu : iv;
          const u32 key =
              (iv << 12) | (codeBase + waveM + mi * 16 + quad * 4 + r);
          if (key < b0) { b1 = b0; b0 = key; }
          else if (key < b1) { b1 = key; }
        }
#pragma unroll
      for (int off = 16; off < 64; off <<= 1) {
        const u32 o0 = __shfl_xor(b0, off);
        const u32 o1 = __shfl_xor(b1, off);
        const u32 n0 = min(b0, o0);
        const u32 n1 = min(max(b0, o0), min(b1, o1));
        b0 = n0; b1 = n1;
      }
      if (quad == 0) {
        const int rloc = waveN + ni * 16 + l15;
        wred[rloc * 4 + (w & 1) * 2 + 0] = b0;
        wred[rloc * 4 + (w & 1) * 2 + 1] = b1;
      }
    }
    // wred writes + cur bf reads retired, then barrier (cur freed for t+1's
    // STAGE; wred visible for merge)
    lds_fence_barrier_pre();
    if (tid < 128) {
      const u32 a0 = wred[tid * 4 + 0], a1 = wred[tid * 4 + 1];
      const u32 c0 = wred[tid * 4 + 2], c1 = wred[tid * 4 + 3];
      const u32 b0 = min(a0, c0);
      const u32 b1 = min(max(a0, c0), min(a1, c1));
      u32* dst = cand + (size_t)(rowBase + tid) * (2 * nx) + 2 * ct;
      *(u64*)dst = ((u64)b1 << 32) | b0;
    }
    // merge reads of t complete before any wred write of t+1: writers pass
    // the next iteration's barrier first.
  }
}

// ===========================================================================
// Stage-2 rerank — R13 (unchanged).
// ===========================================================================
template <int K, int NC, int LEVEL>
__global__ __launch_bounds__(256, 4) void rerank_kernel(
    const u32* __restrict__ cand, const u16* __restrict__ zes,
    const float* __restrict__ cb, const float* __restrict__ cbn,
    float* __restrict__ outq, u16* __restrict__ wsq,
    float* __restrict__ out_idx, float* __restrict__ psum) {
  constexpr int DV = K / 32;  // float4-chunks per lane dot slice (8 z / 4 q)
  constexpr int MV = K / 64;  // MSE elems per lane (4 z / 2 q)
  const int w = threadIdx.x >> 6, lane = threadIdx.x & 63;
  const int row = blockIdx.x * 4 + w;
  const int g = lane >> 3, sub = lane & 7;

  const u16* zr = zes + (size_t)row * 2 * K;

  // ---- phase 1: batch-issue all row-dependent loads ----
  ushort4 zh[DV], zl[DV];
#pragma unroll
  for (int i = 0; i < DV; ++i) {
    zh[i] = *(const ushort4*)(zr + sub * (K / 8) + 4 * i);
    zl[i] = *(const ushort4*)(zr + K + sub * (K / 8) + 4 * i);
  }
  float zmse[MV];
#pragma unroll
  for (int i = 0; i < MV; ++i) {
    const int c = lane + 64 * i;
    zmse[i] = bf16_to_f(zr[c]) + bf16_to_f(zr[K + c]);
  }
  const u32 mykey = (lane < NC) ? cand[(size_t)row * NC + lane] : ~0u;

  // ---- phase 2: top-8 by rank (LDS broadcast) ----
  __shared__ u32 kb[4][72];
  kb[w][lane] = mykey;
  __syncthreads();
  int rank = 0;
#pragma unroll
  for (int j = 0; j < 64; ++j) {
    const u32 kj = kb[w][j];
    rank += (kj < mykey || (kj == mykey && j < lane)) ? 1 : 0;
  }
  if (rank < 8) kb[w][64 + rank] = mykey;
  __syncthreads();
  const unsigned ci = kb[w][64 + g] & 0xFFFu;

  // ---- phase 3: exact f32 dot for this group's candidate ----
  const float* cr = cb + (size_t)ci * K;
  float dot = 0.f;
#pragma unroll
  for (int i = 0; i < DV; ++i) {
    const float4 cv = *(const float4*)(cr + sub * (K / 8) + 4 * i);
    dot = fmaf(bf16_to_f(zh[i].x) + bf16_to_f(zl[i].x), cv.x, dot);
    dot = fmaf(bf16_to_f(zh[i].y) + bf16_to_f(zl[i].y), cv.y, dot);
    dot = fmaf(bf16_to_f(zh[i].z) + bf16_to_f(zl[i].z), cv.z, dot);
    dot = fmaf(bf16_to_f(zh[i].w) + bf16_to_f(zl[i].w), cv.w, dot);
  }
#pragma unroll
  for (int off = 1; off < 8; off <<= 1) dot += __shfl_xor(dot, off);
  u64 k2 = pack_key(cbn[ci] - 2.0f * dot, ci);
#pragma unroll
  for (int off = 8; off < 64; off <<= 1) k2 = min64(k2, __shfl_xor(k2, off));
  const unsigned best = (unsigned)k2;
  if (lane == 0) out_idx[row] = (float)best;

  // ---- phase 4: gather best row, MSE + writes ----
  const float* br = cb + (size_t)best * K;
  float local = 0.f;
#pragma unroll
  for (int i = 0; i < MV; ++i) {
    const int c = lane + 64 * i;
    const float v = br[c];
    const float d = zmse[i] - v;
    local += d * d;
    outq[(size_t)row * K + c] = v;
    if (LEVEL == 0) {
      const u16 h = bf16_rne(v);
      wsq[(size_t)row * 2 * K + c] = h;
      wsq[(size_t)row * 2 * K + K + c] = bf16_rne(v - bf16_to_f(h));
    } else {
      wsq[(size_t)row * K + c] = bf16_rne(v);
    }
  }
#pragma unroll
  for (int o = 32; o > 0; o >>= 1) local += __shfl_down(local, o);
  __shared__ float p[4];
  if (lane == 0) p[w] = local;
  __syncthreads();
  if (threadIdx.x == 0) psum[blockIdx.x] = p[0] + p[1] + p[2] + p[3];
}

// ===========================================================================
// Finalize: sum the per-block partials (8192 z + 8192 q + 1024 recon).
// ===========================================================================
__global__ void finalize_kernel(const float* __restrict__ psumZ,
                                const float* __restrict__ psumQ,
                                const float* __restrict__ psumR,
                                float* __restrict__ out) {
  const int tid = threadIdx.x;
  float sz = 0.f, sq = 0.f, sr = 0.f;
  for (int i = tid; i < 8192; i += 256) {
    sz += psumZ[i];
    sq += psumQ[i];
  }
  for (int i = tid; i < 1024; i += 256) sr += psumR[i];
#pragma unroll
  for (int o = 32; o > 0; o >>= 1) {
    sz += __shfl_down(sz, o);
    sq += __shfl_down(sq, o);
    sr += __shfl_down(sr, o);
  }
  __shared__ float pz[4], pq[4], pr[4];
  if ((tid & 63) == 0) {
    pz[tid >> 6] = sz;
    pq[tid >> 6] = sq;
    pr[tid >> 6] = sr;
  }
  __syncthreads();
  if (tid == 0) {
    const float cz = (pz[0] + pz[1] + pz[2] + pz[3]) / ((float)kBatch * 256.f);
    const float cq = (pq[0] + pq[1] + pq[2] + pq[3]) / ((float)kBatch * 128.f);
    const float rec = (pr[0] + pr[1] + pr[2] + pr[3]) / ((float)kBatch * 512.f);
    out[0] = rec + 0.5f * cz + 0.5f * cq;
    out[1] = rec;
    out[2] = cz;
    out[3] = cz;
    out[4] = cq;
    out[5] = cq;
  }
}

}  // namespace

extern "C" void kernel_launch(void* const* d_in, const int* in_sizes, int n_in,
                              void* d_out, int out_size, void* d_ws,
                              size_t ws_size, hipStream_t stream) {
  const float* x   = (const float*)d_in[0];
  const float* eW1 = (const float*)d_in[1];
  const float* eb1 = (const float*)d_in[2];
  const float* eW2 = (const float*)d_in[3];
  const float* eb2 = (const float*)d_in[4];
  const float* zW  = (const float*)d_in[5];
  const float* zb  = (const float*)d_in[6];
  const float* zci = (const float*)d_in[7];
  const float* zcb = (const float*)d_in[8];
  const float* qW  = (const float*)d_in[9];
  const float* qb  = (const float*)d_in[10];
  const float* qci = (const float*)d_in[11];
  const float* qcb = (const float*)d_in[12];
  const float* dW1 = (const float*)d_in[13];
  const float* db1 = (const float*)d_in[14];
  const float* dW2 = (const float*)d_in[15];
  const float* db2 = (const float*)d_in[16];
  const float* oW  = (const float*)d_in[17];
  const float* ob  = (const float*)d_in[18];

  float* out = (float*)d_out;
  float* out_xr = out + 6;
  float* out_zq = out_xr + (size_t)32768 * 512;
  float* out_qq = out_zq + (size_t)32768 * 256;
  float* out_zi = out_qq + (size_t)32768 * 128;
  float* out_qi = out_zi + 32768;

  // ---- workspace layout ---------------------------------------------------
  char* wsb = (char*)d_ws;
  u16*  zWns = (u16*) (wsb + 0x0000000);  // 256 x 1536  768K
  u16*  qWns = (u16*) (wsb + 0x00C0000);  // 128 x 768   192K
  u16*  eW1s = (u16*) (wsb + 0x00F0000);  // 64 x 1536   192K
  u16*  eW2s = (u16*) (wsb + 0x0120000);  // 512 x 192   192K
  u16*  dW1b = (u16*) (wsb + 0x0150000);  // 64x128       16K
  u16*  dW2b = (u16*) (wsb + 0x0154000);  // 512x64       64K
  u16*  oWb  = (u16*) (wsb + 0x0164000);  // 512x512     512K
  u16*  zcbh = (u16*) (wsb + 0x01E4000);  // 4096x256      2M
  u16*  qcbh = (u16*) (wsb + 0x03E4000);  // 2048x128    512K
  float* zcbn = (float*)(wsb + 0x0464000); // 16K
  float* qcbn = (float*)(wsb + 0x0468000); // 8K
  float* psumR = (float*)(wsb + 0x046B000); // 1024 f32 = 4K
  float* psumZ = (float*)(wsb + 0x0470000); // 8192 f32 = 32K
  float* psumQ = (float*)(wsb + 0x0478000); // 8192 f32 = 32K
  // time-windowed regions:
  u16*  h1s  = (u16*) (wsb + 0x0480000);  // 8M  [enc1 -> enc2]
  u16*  h1b  = (u16*) (wsb + 0x0480000);  //   4M [dec1 -> dec2]
  u16*  zes  = (u16*) (wsb + 0x0C80000);  // 32M [zproj -> zdist,zrerank]
  u16*  qes  = (u16*) (wsb + 0x0C80000);  //   16M [qproj -> qdist,qrerank]
  u16*  hb   = (u16*) (wsb + 0x0C80000);  //   32M [dec2 -> recon]
  u16*  xs   = (u16*) (wsb + 0x2C80000);  // 64M [cast -> enc1]
  u16*  hs   = (u16*) (wsb + 0x2C80000);  //   64M [enc2 -> zproj]
  u32*  candz = (u32*)(wsb + 0x2C80000);  //   8M [zdist -> zrerank]
  u16*  zqs  = (u16*) (wsb + 0x3480000);  //   32M [zrerank -> qproj]
  u32*  candq = (u32*)(wsb + 0x2C80000);  //   4M [qdist -> qrerank]
  u16*  qqb  = (u16*) (wsb + 0x5480000);  //   8M [qrerank -> dec1]

  // ---- prep (3 launches; no memset needed — partials are plain stores) ----
  prep_cb_kernel<<<1536, 256, 0, stream>>>(zcb, zcbh, zcbn, qcb, qcbh, qcbn);
  prep_w_kernel<<<1824, 256, 0, stream>>>(zW, zci, qW, qci, eW1, eW2, zWns,
                                          qWns, eW1s, eW2s, dW1, dW2, oW,
                                          dW1b, dW2b, oWb);
  cast_split_x_kernel<<<16384, 256, 0, stream>>>(x, xs);

  // ---- encoder ----
  gemm_uni<128, 64, 2, U_GELU_SPLIT><<<dim3(1, 256), 128, 0, stream>>>(
      xs, eW1s, eb1, h1s, nullptr, nullptr, 1536, 1024, 1024, 64);
  gemm_uni<128, 128, 4, U_GELU_SPLIT><<<dim3(4, 256), 256, 0, stream>>>(
      h1s, eW2s, eb2, hs, nullptr, nullptr, 192, 128, 128, 512);
  gemm_uni<128, 128, 4, U_SIG_SPLIT><<<dim3(2, 256), 256, 0, stream>>>(
      hs, zWns, zb, zes, nullptr, nullptr, 1536, 1024, 1024, 256);

  // ---- z quantize: dist2z 64x64 tiles, grid (btg=8, ct=64) = 512 blocks
  //      = 2 blocks/CU (VGPR ~110, LDS 66K); top-1/tile -> cand[row*64+ct]
  dist2z_kernel<256, 64, 64, 64><<<dim3(8, 64), 256, 0, stream>>>(
      zcbh, zes, zcbn, candz, 512, 64);
  rerank_kernel<256, 64, 0><<<8192, 256, 0, stream>>>(
      candz, zes, zcb, zcbn, out_zq, zqs, out_zi, psumZ);

  // ---- q level ----
  gemm_uni<128, 128, 4, U_SIG_SPLIT><<<dim3(1, 256), 256, 0, stream>>>(
      zqs, qWns, qb, qes, nullptr, nullptr, 768, 512, 512, 128);
  dist2p_kernel<128, 8><<<dim3(32, 16), 256, 0, stream>>>(
      qcbh, qes, qcbn, candq, 256, 16);
  rerank_kernel<128, 32, 1><<<8192, 256, 0, stream>>>(
      candq, qes, qcb, qcbn, out_qq, qqb, out_qi, psumQ);

  // ---- decoder ----
  gemm_uni<128, 64, 2, U_GELU_B16><<<dim3(1, 256), 128, 0, stream>>>(
      qqb, dW1b, db1, h1b, nullptr, nullptr, 128, 1 << 30, 128, 64);
  gemm_uni<128, 128, 4, U_GELU_B16><<<dim3(4, 256), 256, 0, stream>>>(
      h1b, dW2b, db2, hb, nullptr, nullptr, 64, 1 << 30, 64, 512);
  gemm_uni<128, 128, 4, U_RECON><<<dim3(4, 256), 256, 0, stream>>>(
      hb, oWb, ob, out_xr, x, psumR, 512, 1 << 30, 512, 512);

  finalize_kernel<<<1, 256, 0, stream>>>(psumZ, psumQ, psumR, out);

  (void)in_sizes; (void)n_in; (void)out_size; (void)ws_size;
}

// Round 9
// 667.430 us; speedup vs baseline: 1.4612x; 1.0331x over previous
//
#include <hip/hip_runtime.h>

typedef unsigned long long u64;
typedef unsigned short u16;
typedef unsigned int u32;

// ---------------------------------------------------------------------------
// HierarchicalLFQHVQVAE forward — R17.
// Base = R16 (689.5 us). R16 post-mortem: small-tile 2-block/CU recipe WORKS
// (occ 11->21%, dur 121->110.5) with the af-hoist intact. Remaining top-5 is
// all dist2z; the known hidden straggler with identical pathology is q-dist
// (dist2p<128,8>: VGPR 160 -> 1 wave/SIMD, 512 blocks = 2 sequential passes).
// R17:
//  1. q-dist ported to the R16 recipe: dist2z_kernel<128,64,64,16>,
//     grid (32,32) = 1024 blocks = 4 blocks/CU (LDS 33KB, VGPR ~64 -> 16
//     waves/CU) = 4 waves/SIMD. Top-1 per 64-code tile -> candq[row*32+ct],
//     NC=32 (q-rerank byte-compatible). Old dist2p_kernel deleted.
//  2. z-dist: in-loop vmcnt(0) -> vmcnt(1) (retires the 8 stage loads,
//     leaves the merge's cand store in flight; oldest-first retirement).
// Everything else identical to R16.
// ---------------------------------------------------------------------------

namespace {

constexpr int kBatch = 32768;

__device__ __forceinline__ float gelu_f(float x) {
  return 0.5f * x * (1.0f + erff(x * 0.70710678118654752440f));
}
__device__ __forceinline__ float sigmoid_f(float x) {
  return 1.0f / (1.0f + expf(-x));
}
__device__ __forceinline__ u64 pack_key(float d, unsigned j) {
  unsigned u = __float_as_uint(d);
  u = (u & 0x80000000u) ? ~u : (u | 0x80000000u);
  return ((u64)u << 32) | j;
}
__device__ __forceinline__ u16 bf16_rne(float x) {
  unsigned u = __float_as_uint(x);
  unsigned r = (u + 0x7FFFu + ((u >> 16) & 1u)) >> 16;
  return (u16)r;
}
__device__ __forceinline__ float bf16_to_f(u16 h) {
  return __uint_as_float((unsigned)h << 16);
}
__device__ __forceinline__ u64 min64(u64 a, u64 b) { return a < b ? a : b; }

__device__ __forceinline__ void load_lds16(const void* g, void* l) {
  __builtin_amdgcn_global_load_lds(
      (const __attribute__((address_space(1))) void*)g,
      (__attribute__((address_space(3))) void*)l, 16, 0, 0);
}

template <int N>
__device__ __forceinline__ void wait_vmcnt() {
  if constexpr (N == 0) {
    asm volatile("s_waitcnt vmcnt(0)" ::: "memory");
  } else if constexpr (N == 1) {
    asm volatile("s_waitcnt vmcnt(1)" ::: "memory");
  } else if constexpr (N == 8) {
    asm volatile("s_waitcnt vmcnt(8)" ::: "memory");
  } else if constexpr (N == 16) {
    asm volatile("s_waitcnt vmcnt(16)" ::: "memory");
  }
}

__device__ __forceinline__ void lds_fence_barrier_pre() {
  // order: all prior LDS ops retired, then barrier
  asm volatile("s_waitcnt lgkmcnt(0)" ::: "memory");
  __builtin_amdgcn_sched_barrier(0);
  __builtin_amdgcn_s_barrier();
  asm volatile("" ::: "memory");  // no LDS op hoists above the barrier
  __builtin_amdgcn_sched_barrier(0);
}

__device__ __forceinline__ void barrier_raw() {
  __builtin_amdgcn_sched_barrier(0);
  __builtin_amdgcn_s_barrier();
  asm volatile("" ::: "memory");  // no LDS op hoists above the barrier
  __builtin_amdgcn_sched_barrier(0);
}

typedef short bf16x8 __attribute__((ext_vector_type(8)));
typedef float f32x4 __attribute__((ext_vector_type(4)));

// ===========================================================================
// Prep (3 kernels) — identical to R6
// ===========================================================================
__global__ void prep_cb_kernel(const float* __restrict__ zcb,
                               u16* __restrict__ zcbh, float* __restrict__ zcbn,
                               const float* __restrict__ qcb,
                               u16* __restrict__ qcbh, float* __restrict__ qcbn) {
  int b = blockIdx.x;
  const float* cb;
  u16* cbh;
  float* cbn;
  int K;
  if (b < 1024) { cb = zcb; cbh = zcbh; cbn = zcbn; K = 256; }
  else { b -= 1024; cb = qcb; cbh = qcbh; cbn = qcbn; K = 128; }
  const int row = b * 4 + (threadIdx.x >> 6);
  const int lane = threadIdx.x & 63;
  double s = 0.0;
  for (int k = lane; k < K; k += 64) {
    const float v = cb[(size_t)row * K + k];
    cbh[(size_t)row * K + k] = bf16_rne(v);
    s += (double)v * (double)v;
  }
#pragma unroll
  for (int o = 32; o > 0; o >>= 1) s += __shfl_down(s, o);
  if (lane == 0) cbn[row] = (float)s;
}

__global__ void prep_w_kernel(
    const float* __restrict__ zW, const float* __restrict__ zci,
    const float* __restrict__ qW, const float* __restrict__ qci,
    const float* __restrict__ eW1, const float* __restrict__ eW2,
    u16* __restrict__ zWns, u16* __restrict__ qWns, u16* __restrict__ eW1s,
    u16* __restrict__ eW2s, const float* __restrict__ dW1,
    const float* __restrict__ dW2, const float* __restrict__ oW,
    u16* __restrict__ dW1b, u16* __restrict__ dW2b, u16* __restrict__ oWb) {
  const int b = blockIdx.x;
  const int tid = threadIdx.x;
  if (b < 384) {
    const float* W;
    const float* ci;
    u16* D;
    int K, row;
    if (b < 256) { W = zW; ci = zci; D = zWns; K = 512; row = b; }
    else { W = qW; ci = qci; D = qWns; K = 256; row = b - 256; }
    float s = 0.f;
    for (int k = tid; k < K; k += 256) s += fabsf(W[(size_t)row * K + k]);
#pragma unroll
    for (int o = 32; o > 0; o >>= 1) s += __shfl_down(s, o);
    __shared__ float p[4];
    if ((tid & 63) == 0) p[tid >> 6] = s;
    __syncthreads();
    const float tot = p[0] + p[1] + p[2] + p[3];
    const float c = ci[row];
    const float sp = (c > 20.f) ? c : log1pf(expf(c));
    const float scale = fminf(1.f, sp / tot);
    for (int k = tid; k < K; k += 256) {
      const float v = W[(size_t)row * K + k] * scale;
      const u16 h = bf16_rne(v);
      const u16 l = bf16_rne(v - bf16_to_f(h));
      D[(size_t)row * 3 * K + k] = h;
      D[(size_t)row * 3 * K + K + k] = h;
      D[(size_t)row * 3 * K + 2 * K + k] = l;
    }
  } else if (b < 512) {  // eW1 split3, 64x512
    const int i = (b - 384) * 256 + tid;
    const int r = i >> 9, k = i & 511;
    const float v = eW1[i];
    const u16 h = bf16_rne(v);
    const u16 l = bf16_rne(v - bf16_to_f(h));
    eW1s[(size_t)r * 1536 + k] = h;
    eW1s[(size_t)r * 1536 + 512 + k] = h;
    eW1s[(size_t)r * 1536 + 1024 + k] = l;
  } else if (b < 640) {  // eW2 split3, 512x64
    const int i = (b - 512) * 256 + tid;
    const int r = i >> 6, k = i & 63;
    const float v = eW2[i];
    const u16 h = bf16_rne(v);
    const u16 l = bf16_rne(v - bf16_to_f(h));
    eW2s[(size_t)r * 192 + k] = h;
    eW2s[(size_t)r * 192 + 64 + k] = h;
    eW2s[(size_t)r * 192 + 128 + k] = l;
  } else if (b < 672) {
    const int i = (b - 640) * 256 + tid;
    dW1b[i] = bf16_rne(dW1[i]);
  } else if (b < 800) {
    const int i = (b - 672) * 256 + tid;
    dW2b[i] = bf16_rne(dW2[i]);
  } else {
    const int i = (b - 800) * 256 + tid;
    oWb[i] = bf16_rne(oW[i]);
  }
}

__global__ void cast_split_x_kernel(const float* __restrict__ x,
                                    u16* __restrict__ xs) {
  const int i = blockIdx.x * 256 + threadIdx.x;
  const int row = i >> 7, c4 = i & 127;
  const float4 v = *(const float4*)(x + (size_t)row * 512 + c4 * 4);
  const float vv[4] = {v.x, v.y, v.z, v.w};
  u16 hv[4], lv[4];
#pragma unroll
  for (int j = 0; j < 4; ++j) {
    hv[j] = bf16_rne(vv[j]);
    lv[j] = bf16_rne(vv[j] - bf16_to_f(hv[j]));
  }
  *(ushort4*)(xs + (size_t)row * 1024 + c4 * 4) =
      make_ushort4(hv[0], hv[1], hv[2], hv[3]);
  *(ushort4*)(xs + (size_t)row * 1024 + 512 + c4 * 4) =
      make_ushort4(lv[0], lv[1], lv[2], lv[3]);
}

// ===========================================================================
// Unified MFMA GEMM (identical to R13).
// ===========================================================================
enum { U_GELU_SPLIT = 0, U_SIG_SPLIT = 1, U_GELU_B16 = 2, U_RECON = 3 };

template <int TM, int TN, int NW, int MODE>
__global__ __launch_bounds__(NW * 64) void gemm_uni(
    const u16* __restrict__ A, const u16* __restrict__ B,
    const float* __restrict__ bias, void* __restrict__ Cv,
    const float* __restrict__ X, float* __restrict__ psum, int Ktot,
    int wrapA, int strideA, int N) {
  __shared__ __align__(16) u16 As[TM * 64];
  __shared__ __align__(16) u16 Bs[TN * 64];
  constexpr int NT = NW * 64;
  constexpr int AIT = (TM * 8) / NT;
  constexpr int BIT = (TN * 8) / NT;
  const int tid = threadIdx.x;
  const int lane = tid & 63, w = tid >> 6;
  const int quad = lane >> 4, l15 = lane & 15;
  const int waveM = (TN == 64) ? w * 64 : (w & 1) * 64;
  const int waveN = (TN == 64) ? 0 : (w >> 1) * 64;
  const int rowBase = blockIdx.y * TM;
  const int colBase = blockIdx.x * TN;

  f32x4 acc[4][4] = {};

  for (int k0 = 0; k0 < Ktot; k0 += 64) {
    const int sk0 = (k0 >= wrapA) ? k0 - wrapA : k0;
    __syncthreads();
#pragma unroll
    for (int i = 0; i < AIT; ++i) {
      const int ch = i * NT + tid;
      const int r = ch >> 3, c = ch & 7, g = c ^ (r & 7);
      load_lds16(A + (size_t)(rowBase + r) * strideA + sk0 + g * 8,
                 (char*)As + ch * 16);
    }
#pragma unroll
    for (int i = 0; i < BIT; ++i) {
      const int ch = i * NT + tid;
      const int r = ch >> 3, c = ch & 7, g = c ^ (r & 7);
      load_lds16(B + (size_t)(colBase + r) * Ktot + k0 + g * 8,
                 (char*)Bs + ch * 16);
    }
    __syncthreads();
#pragma unroll
    for (int ks = 0; ks < 2; ++ks) {
      bf16x8 af[4], bf[4];
      const int ch = ks * 4 + quad;
#pragma unroll
      for (int mi = 0; mi < 4; ++mi) {
        const int rl = waveM + mi * 16 + l15;
        af[mi] = *(const bf16x8*)(As + rl * 64 + (ch ^ (rl & 7)) * 8);
      }
#pragma unroll
      for (int ni = 0; ni < 4; ++ni) {
        const int rl = waveN + ni * 16 + l15;
        bf[ni] = *(const bf16x8*)(Bs + rl * 64 + (ch ^ (rl & 7)) * 8);
      }
#pragma unroll
      for (int mi = 0; mi < 4; ++mi)
#pragma unroll
        for (int ni = 0; ni < 4; ++ni)
          acc[mi][ni] = __builtin_amdgcn_mfma_f32_16x16x32_bf16(
              af[mi], bf[ni], acc[mi][ni], 0, 0, 0);
    }
  }

  if constexpr (MODE == U_GELU_SPLIT || MODE == U_SIG_SPLIT) {
    u16* S = (u16*)Cv;
#pragma unroll
    for (int mi = 0; mi < 4; ++mi)
#pragma unroll
      for (int r = 0; r < 4; ++r) {
        const int row = rowBase + waveM + mi * 16 + quad * 4 + r;
#pragma unroll
        for (int ni = 0; ni < 4; ++ni) {
          const int col = colBase + waveN + ni * 16 + l15;
          const float pre = acc[mi][ni][r] + bias[col];
          const float v = (MODE == U_GELU_SPLIT) ? gelu_f(pre) : sigmoid_f(pre);
          const u16 h = bf16_rne(v);
          const u16 l = bf16_rne(v - bf16_to_f(h));
          S[(size_t)row * 2 * N + col] = h;
          S[(size_t)row * 2 * N + N + col] = l;
        }
      }
  } else if constexpr (MODE == U_GELU_B16) {
    u16* C = (u16*)Cv;
#pragma unroll
    for (int mi = 0; mi < 4; ++mi)
#pragma unroll
      for (int r = 0; r < 4; ++r) {
        const int row = rowBase + waveM + mi * 16 + quad * 4 + r;
#pragma unroll
        for (int ni = 0; ni < 4; ++ni) {
          const int col = colBase + waveN + ni * 16 + l15;
          C[(size_t)row * N + col] =
              bf16_rne(gelu_f(acc[mi][ni][r] + bias[col]));
        }
      }
  } else {  // U_RECON
    float* C = (float*)Cv;
    float local = 0.f;
#pragma unroll
    for (int mi = 0; mi < 4; ++mi)
#pragma unroll
      for (int r = 0; r < 4; ++r) {
        const int row = rowBase + waveM + mi * 16 + quad * 4 + r;
#pragma unroll
        for (int ni = 0; ni < 4; ++ni) {
          const int col = colBase + waveN + ni * 16 + l15;
          const float val = acc[mi][ni][r] + bias[col];
          const float d = val - X[(size_t)row * N + col];
          local += d * d;
          C[(size_t)row * N + col] = val;
        }
      }
#pragma unroll
    for (int o = 32; o > 0; o >>= 1) local += __shfl_down(local, o);
    __shared__ float psh[NW];
    if (lane == 0) psh[w] = local;
    __syncthreads();
    if (tid == 0) {
      float t = 0.f;
#pragma unroll
      for (int i = 0; i < NW; ++i) t += psh[i];
      psum[blockIdx.y * gridDim.x + blockIdx.x] = t;  // unique slot, no atomic
    }
  }
}

// ===========================================================================
// Stage-1 distance — R16/R17 dist2z: CT codes x BR rows per block, small
// tiles so multiple blocks pack per CU (the only stall-hiding mechanism
// with measured effect; R9/R14/R15 ledger).
//   z: <256,64,64,64> grid (8,64)  = 512 blocks  = 2 blocks/CU (LDS 66K)
//   q: <128,64,64,16> grid (32,32) = 1024 blocks = 4 blocks/CU (LDS 33K)
// bufC persistent + af hoist; bufB single-buffered. Top-1 per tile ->
// cand[row*ncand + ct]. Per iter: MFMA -> epi -> fence -> issue stage(t+1)
// -> merge under DMA -> vmcnt(1) (stages drained, cand store left in
// flight) -> fence.
// ===========================================================================
template <int KT, int CT, int BR, int BTG>
__global__ __launch_bounds__(256) void dist2z_kernel(
    const u16* __restrict__ CB, const u16* __restrict__ ZB,
    const float* __restrict__ cbn, u32* __restrict__ cand, int strideB,
    int ncand) {
  constexpr int CH = KT / 8;               // 16B-chunks per row
  constexpr int KSTEPS = KT / 32;
  constexpr int CSLOTS = (CT * CH) / 256;
  constexpr int BSLOTS = (BR * CH) / 256;
  __shared__ __align__(16) u16 bufC[CT * KT];  // codebook, persistent
  __shared__ __align__(16) u16 bufB[BR * KT];  // batch tile
  __shared__ u32 wred[BR * 2];
  const int tid = threadIdx.x;
  const int lane = tid & 63, w = tid >> 6;
  const int quad = lane >> 4, l15 = lane & 15;
  const int waveM = (w & 1) * 32;   // code half (32 codes)
  const int waveN = (w >> 1) * 32;  // batch half (32 rows)
  const int ct = blockIdx.y;
  const int btg = blockIdx.x;
  const int codeBase = ct * CT;

  float cnf[2][4];
#pragma unroll
  for (int mi = 0; mi < 2; ++mi)
#pragma unroll
    for (int r = 0; r < 4; ++r)
      cnf[mi][r] =
          cbn[codeBase + waveM + mi * 16 + quad * 4 + r] * 512.0f + 131072.0f;
  asm volatile("" ::: "memory");

  // ---- stage codebook -> bufC, batch tile 0 -> bufB ----
#pragma unroll
  for (int i = 0; i < CSLOTS; ++i) {
    const int ch = i * 256 + tid;
    const int r = ch / CH, c = ch % CH, g = c ^ (r & 7);
    load_lds16(CB + (size_t)(codeBase + r) * KT + g * 8, (char*)bufC + ch * 16);
  }
  {
    const int rowBase0 = btg * BTG * BR;
#pragma unroll
    for (int i = 0; i < BSLOTS; ++i) {
      const int ch = i * 256 + tid;
      const int r = ch / CH, c = ch % CH, g = c ^ (r & 7);
      load_lds16(ZB + (size_t)(rowBase0 + r) * strideB + g * 8,
                 (char*)bufB + ch * 16);
    }
  }
  wait_vmcnt<0>();
  barrier_raw();

  // ---- hoist A fragments; bufC never written again ----
  bf16x8 af[KSTEPS][2];
#pragma unroll
  for (int kk = 0; kk < KSTEPS; ++kk)
#pragma unroll
    for (int mi = 0; mi < 2; ++mi) {
      const int rl = waveM + mi * 16 + l15;
      const int sw = (kk * 4 + quad) ^ (rl & 7);
      af[kk][mi] = *(const bf16x8*)(bufC + rl * KT + sw * 8);
    }

#pragma unroll 1
  for (int bt = 0; bt < BTG; ++bt) {
    const int rowBase = (btg * BTG + bt) * BR;

    // ---- MFMA over bufB(bt) ----
    f32x4 acc[2][2] = {};
#pragma unroll
    for (int kk = 0; kk < KSTEPS; ++kk) {
      bf16x8 bf[2];
#pragma unroll
      for (int ni = 0; ni < 2; ++ni) {
        const int rn = waveN + ni * 16 + l15;
        const int sw = (kk * 4 + quad) ^ (rn & 7);
        bf[ni] = *(const bf16x8*)(bufB + rn * KT + sw * 8);
      }
#pragma unroll
      for (int mi = 0; mi < 2; ++mi)
#pragma unroll
        for (int ni = 0; ni < 2; ++ni)
          acc[mi][ni] = __builtin_amdgcn_mfma_f32_16x16x32_bf16(
              af[kk][mi], bf[ni], acc[mi][ni], 0, 0, 0);
    }

    // ---- epilogue: top-1 per batch row over this wave's 32 codes ----
#pragma unroll
    for (int ni = 0; ni < 2; ++ni) {
      u32 b0 = ~0u;
#pragma unroll
      for (int mi = 0; mi < 2; ++mi)
#pragma unroll
        for (int r = 0; r < 4; ++r) {
          const float kf = fmaf(acc[mi][ni][r], -1024.0f, cnf[mi][r]);
          u32 iv = (u32)kf;
          iv = iv > 0xFFFFFu ? 0xFFFFFu : iv;
          const u32 key =
              (iv << 12) | (codeBase + waveM + mi * 16 + quad * 4 + r);
          b0 = min(b0, key);
        }
      b0 = min(b0, (u32)__shfl_xor(b0, 16));
      b0 = min(b0, (u32)__shfl_xor(b0, 32));
      if (quad == 0) {
        const int rloc = waveN + ni * 16 + l15;
        wred[rloc * 2 + (w & 1)] = b0;
      }
    }
    // bufB reads + wred writes retired, then barrier
    lds_fence_barrier_pre();

    // ---- issue next tile's staging (DMA runs under the merge) ----
    if (bt + 1 < BTG) {
      const int rowBaseN = rowBase + BR;
#pragma unroll
      for (int i = 0; i < BSLOTS; ++i) {
        const int ch = i * 256 + tid;
        const int r = ch / CH, c = ch % CH, g = c ^ (r & 7);
        load_lds16(ZB + (size_t)(rowBaseN + r) * strideB + g * 8,
                   (char*)bufB + ch * 16);
      }
    }
    // ---- merge + store (reads wred(bt), safe vs stage: different region) --
    if (tid < BR) {
      const u32 m0 = min(wred[tid * 2 + 0], wred[tid * 2 + 1]);
      cand[(size_t)(rowBase + tid) * ncand + ct] = m0;
    }
    wait_vmcnt<1>();          // stages drained (cand store stays in flight)
    lds_fence_barrier_pre();  // visible to all; merge reads drained
  }
}

// ===========================================================================
// Stage-2 rerank — R13 (unchanged).
// ===========================================================================
template <int K, int NC, int LEVEL>
__global__ __launch_bounds__(256, 4) void rerank_kernel(
    const u32* __restrict__ cand, const u16* __restrict__ zes,
    const float* __restrict__ cb, const float* __restrict__ cbn,
    float* __restrict__ outq, u16* __restrict__ wsq,
    float* __restrict__ out_idx, float* __restrict__ psum) {
  constexpr int DV = K / 32;  // float4-chunks per lane dot slice (8 z / 4 q)
  constexpr int MV = K / 64;  // MSE elems per lane (4 z / 2 q)
  const int w = threadIdx.x >> 6, lane = threadIdx.x & 63;
  const int row = blockIdx.x * 4 + w;
  const int g = lane >> 3, sub = lane & 7;

  const u16* zr = zes + (size_t)row * 2 * K;

  // ---- phase 1: batch-issue all row-dependent loads ----
  ushort4 zh[DV], zl[DV];
#pragma unroll
  for (int i = 0; i < DV; ++i) {
    zh[i] = *(const ushort4*)(zr + sub * (K / 8) + 4 * i);
    zl[i] = *(const ushort4*)(zr + K + sub * (K / 8) + 4 * i);
  }
  float zmse[MV];
#pragma unroll
  for (int i = 0; i < MV; ++i) {
    const int c = lane + 64 * i;
    zmse[i] = bf16_to_f(zr[c]) + bf16_to_f(zr[K + c]);
  }
  const u32 mykey = (lane < NC) ? cand[(size_t)row * NC + lane] : ~0u;

  // ---- phase 2: top-8 by rank (LDS broadcast) ----
  __shared__ u32 kb[4][72];
  kb[w][lane] = mykey;
  __syncthreads();
  int rank = 0;
#pragma unroll
  for (int j = 0; j < 64; ++j) {
    const u32 kj = kb[w][j];
    rank += (kj < mykey || (kj == mykey && j < lane)) ? 1 : 0;
  }
  if (rank < 8) kb[w][64 + rank] = mykey;
  __syncthreads();
  const unsigned ci = kb[w][64 + g] & 0xFFFu;

  // ---- phase 3: exact f32 dot for this group's candidate ----
  const float* cr = cb + (size_t)ci * K;
  float dot = 0.f;
#pragma unroll
  for (int i = 0; i < DV; ++i) {
    const float4 cv = *(const float4*)(cr + sub * (K / 8) + 4 * i);
    dot = fmaf(bf16_to_f(zh[i].x) + bf16_to_f(zl[i].x), cv.x, dot);
    dot = fmaf(bf16_to_f(zh[i].y) + bf16_to_f(zl[i].y), cv.y, dot);
    dot = fmaf(bf16_to_f(zh[i].z) + bf16_to_f(zl[i].z), cv.z, dot);
    dot = fmaf(bf16_to_f(zh[i].w) + bf16_to_f(zl[i].w), cv.w, dot);
  }
#pragma unroll
  for (int off = 1; off < 8; off <<= 1) dot += __shfl_xor(dot, off);
  u64 k2 = pack_key(cbn[ci] - 2.0f * dot, ci);
#pragma unroll
  for (int off = 8; off < 64; off <<= 1) k2 = min64(k2, __shfl_xor(k2, off));
  const unsigned best = (unsigned)k2;
  if (lane == 0) out_idx[row] = (float)best;

  // ---- phase 4: gather best row, MSE + writes ----
  const float* br = cb + (size_t)best * K;
  float local = 0.f;
#pragma unroll
  for (int i = 0; i < MV; ++i) {
    const int c = lane + 64 * i;
    const float v = br[c];
    const float d = zmse[i] - v;
    local += d * d;
    outq[(size_t)row * K + c] = v;
    if (LEVEL == 0) {
      const u16 h = bf16_rne(v);
      wsq[(size_t)row * 2 * K + c] = h;
      wsq[(size_t)row * 2 * K + K + c] = bf16_rne(v - bf16_to_f(h));
    } else {
      wsq[(size_t)row * K + c] = bf16_rne(v);
    }
  }
#pragma unroll
  for (int o = 32; o > 0; o >>= 1) local += __shfl_down(local, o);
  __shared__ float p[4];
  if (lane == 0) p[w] = local;
  __syncthreads();
  if (threadIdx.x == 0) psum[blockIdx.x] = p[0] + p[1] + p[2] + p[3];
}

// ===========================================================================
// Finalize: sum the per-block partials (8192 z + 8192 q + 1024 recon).
// ===========================================================================
__global__ void finalize_kernel(const float* __restrict__ psumZ,
                                const float* __restrict__ psumQ,
                                const float* __restrict__ psumR,
                                float* __restrict__ out) {
  const int tid = threadIdx.x;
  float sz = 0.f, sq = 0.f, sr = 0.f;
  for (int i = tid; i < 8192; i += 256) {
    sz += psumZ[i];
    sq += psumQ[i];
  }
  for (int i = tid; i < 1024; i += 256) sr += psumR[i];
#pragma unroll
  for (int o = 32; o > 0; o >>= 1) {
    sz += __shfl_down(sz, o);
    sq += __shfl_down(sq, o);
    sr += __shfl_down(sr, o);
  }
  __shared__ float pz[4], pq[4], pr[4];
  if ((tid & 63) == 0) {
    pz[tid >> 6] = sz;
    pq[tid >> 6] = sq;
    pr[tid >> 6] = sr;
  }
  __syncthreads();
  if (tid == 0) {
    const float cz = (pz[0] + pz[1] + pz[2] + pz[3]) / ((float)kBatch * 256.f);
    const float cq = (pq[0] + pq[1] + pq[2] + pq[3]) / ((float)kBatch * 128.f);
    const float rec = (pr[0] + pr[1] + pr[2] + pr[3]) / ((float)kBatch * 512.f);
    out[0] = rec + 0.5f * cz + 0.5f * cq;
    out[1] = rec;
    out[2] = cz;
    out[3] = cz;
    out[4] = cq;
    out[5] = cq;
  }
}

}  // namespace

extern "C" void kernel_launch(void* const* d_in, const int* in_sizes, int n_in,
                              void* d_out, int out_size, void* d_ws,
                              size_t ws_size, hipStream_t stream) {
  const float* x   = (const float*)d_in[0];
  const float* eW1 = (const float*)d_in[1];
  const float* eb1 = (const float*)d_in[2];
  const float* eW2 = (const float*)d_in[3];
  const float* eb2 = (const float*)d_in[4];
  const float* zW  = (const float*)d_in[5];
  const float* zb  = (const float*)d_in[6];
  const float* zci = (const float*)d_in[7];
  const float* zcb = (const float*)d_in[8];
  const float* qW  = (const float*)d_in[9];
  const float* qb  = (const float*)d_in[10];
  const float* qci = (const float*)d_in[11];
  const float* qcb = (const float*)d_in[12];
  const float* dW1 = (const float*)d_in[13];
  const float* db1 = (const float*)d_in[14];
  const float* dW2 = (const float*)d_in[15];
  const float* db2 = (const float*)d_in[16];
  const float* oW  = (const float*)d_in[17];
  const float* ob  = (const float*)d_in[18];

  float* out = (float*)d_out;
  float* out_xr = out + 6;
  float* out_zq = out_xr + (size_t)32768 * 512;
  float* out_qq = out_zq + (size_t)32768 * 256;
  float* out_zi = out_qq + (size_t)32768 * 128;
  float* out_qi = out_zi + 32768;

  // ---- workspace layout ---------------------------------------------------
  char* wsb = (char*)d_ws;
  u16*  zWns = (u16*) (wsb + 0x0000000);  // 256 x 1536  768K
  u16*  qWns = (u16*) (wsb + 0x00C0000);  // 128 x 768   192K
  u16*  eW1s = (u16*) (wsb + 0x00F0000);  // 64 x 1536   192K
  u16*  eW2s = (u16*) (wsb + 0x0120000);  // 512 x 192   192K
  u16*  dW1b = (u16*) (wsb + 0x0150000);  // 64x128       16K
  u16*  dW2b = (u16*) (wsb + 0x0154000);  // 512x64       64K
  u16*  oWb  = (u16*) (wsb + 0x0164000);  // 512x512     512K
  u16*  zcbh = (u16*) (wsb + 0x01E4000);  // 4096x256      2M
  u16*  qcbh = (u16*) (wsb + 0x03E4000);  // 2048x128    512K
  float* zcbn = (float*)(wsb + 0x0464000); // 16K
  float* qcbn = (float*)(wsb + 0x0468000); // 8K
  float* psumR = (float*)(wsb + 0x046B000); // 1024 f32 = 4K
  float* psumZ = (float*)(wsb + 0x0470000); // 8192 f32 = 32K
  float* psumQ = (float*)(wsb + 0x0478000); // 8192 f32 = 32K
  // time-windowed regions:
  u16*  h1s  = (u16*) (wsb + 0x0480000);  // 8M  [enc1 -> enc2]
  u16*  h1b  = (u16*) (wsb + 0x0480000);  //   4M [dec1 -> dec2]
  u16*  zes  = (u16*) (wsb + 0x0C80000);  // 32M [zproj -> zdist,zrerank]
  u16*  qes  = (u16*) (wsb + 0x0C80000);  //   16M [qproj -> qdist,qrerank]
  u16*  hb   = (u16*) (wsb + 0x0C80000);  //   32M [dec2 -> recon]
  u16*  xs   = (u16*) (wsb + 0x2C80000);  // 64M [cast -> enc1]
  u16*  hs   = (u16*) (wsb + 0x2C80000);  //   64M [enc2 -> zproj]
  u32*  candz = (u32*)(wsb + 0x2C80000);  //   8M [zdist -> zrerank]
  u16*  zqs  = (u16*) (wsb + 0x3480000);  //   32M [zrerank -> qproj]
  u32*  candq = (u32*)(wsb + 0x2C80000);  //   4M [qdist -> qrerank]
  u16*  qqb  = (u16*) (wsb + 0x5480000);  //   8M [qrerank -> dec1]

  // ---- prep (3 launches; no memset needed — partials are plain stores) ----
  prep_cb_kernel<<<1536, 256, 0, stream>>>(zcb, zcbh, zcbn, qcb, qcbh, qcbn);
  prep_w_kernel<<<1824, 256, 0, stream>>>(zW, zci, qW, qci, eW1, eW2, zWns,
                                          qWns, eW1s, eW2s, dW1, dW2, oW,
                                          dW1b, dW2b, oWb);
  cast_split_x_kernel<<<16384, 256, 0, stream>>>(x, xs);

  // ---- encoder ----
  gemm_uni<128, 64, 2, U_GELU_SPLIT><<<dim3(1, 256), 128, 0, stream>>>(
      xs, eW1s, eb1, h1s, nullptr, nullptr, 1536, 1024, 1024, 64);
  gemm_uni<128, 128, 4, U_GELU_SPLIT><<<dim3(4, 256), 256, 0, stream>>>(
      h1s, eW2s, eb2, hs, nullptr, nullptr, 192, 128, 128, 512);
  gemm_uni<128, 128, 4, U_SIG_SPLIT><<<dim3(2, 256), 256, 0, stream>>>(
      hs, zWns, zb, zes, nullptr, nullptr, 1536, 1024, 1024, 256);

  // ---- z quantize: dist2z 64x64 tiles, grid (8,64) = 512 blocks = 2/CU
  dist2z_kernel<256, 64, 64, 64><<<dim3(8, 64), 256, 0, stream>>>(
      zcbh, zes, zcbn, candz, 512, 64);
  rerank_kernel<256, 64, 0><<<8192, 256, 0, stream>>>(
      candz, zes, zcb, zcbn, out_zq, zqs, out_zi, psumZ);

  // ---- q level: dist2z 64x64 tiles, grid (32,32) = 1024 blocks = 4/CU ----
  gemm_uni<128, 128, 4, U_SIG_SPLIT><<<dim3(1, 256), 256, 0, stream>>>(
      zqs, qWns, qb, qes, nullptr, nullptr, 768, 512, 512, 128);
  dist2z_kernel<128, 64, 64, 16><<<dim3(32, 32), 256, 0, stream>>>(
      qcbh, qes, qcbn, candq, 256, 32);
  rerank_kernel<128, 32, 1><<<8192, 256, 0, stream>>>(
      candq, qes, qcb, qcbn, out_qq, qqb, out_qi, psumQ);

  // ---- decoder ----
  gemm_uni<128, 64, 2, U_GELU_B16><<<dim3(1, 256), 128, 0, stream>>>(
      qqb, dW1b, db1, h1b, nullptr, nullptr, 128, 1 << 30, 128, 64);
  gemm_uni<128, 128, 4, U_GELU_B16><<<dim3(4, 256), 256, 0, stream>>>(
      h1b, dW2b, db2, hb, nullptr, nullptr, 64, 1 << 30, 64, 512);
  gemm_uni<128, 128, 4, U_RECON><<<dim3(4, 256), 256, 0, stream>>>(
      hb, oWb, ob, out_xr, x, psumR, 512, 1 << 30, 512, 512);

  finalize_kernel<<<1, 256, 0, stream>>>(psumZ, psumQ, psumR, out);

  (void)in_sizes; (void)n_in; (void)out_size; (void)ws_size;
}